// Round 2
// baseline (3122.979 us; speedup 1.0000x reference)
//
#include <hip/hip_runtime.h>
#include <hip/hip_bf16.h>
#include <math.h>

// ---- problem constants ----
#define NH   16
#define HD   128
#define HID  2048
#define NKV  6144      // 3*NH*HD
#define B_   2
#define S_   2048
#define NC   32        // S/CHUNK
#define CHUNK_ 64
#define GROUPS_ 8

__device__ __forceinline__ float b2f(unsigned int u) {
    union { unsigned int u; float f; } c; c.u = (u & 0xffffu) << 16; return c.f;
}
__device__ __forceinline__ unsigned short f2b(float f) {
    union { float f; unsigned int u; } c; c.f = f;
    unsigned int u = c.u;
    unsigned int r = (u + 0x7fffu + ((u >> 16) & 1u)) >> 16;
    return (unsigned short)r;
}

// ---------------- GEMM: C[M,N] = A[M,K] @ B[K,N], fp32 in, fp32 acc, OutT out ---
// 128x128 tile, BK=16, 256 threads, 8x8 per thread. M,N,K divisible by 128/128/16.
#define BM 128
#define BN 128
#define BKg 16

__device__ __forceinline__ void storeC8(float* cp, const float* acc) {
    *(float4*)cp       = make_float4(acc[0], acc[1], acc[2], acc[3]);
    *(float4*)(cp + 4) = make_float4(acc[4], acc[5], acc[6], acc[7]);
}
__device__ __forceinline__ void storeC8(unsigned short* cp, const float* acc) {
    uint4 pk;
    pk.x = (unsigned)f2b(acc[0]) | ((unsigned)f2b(acc[1]) << 16);
    pk.y = (unsigned)f2b(acc[2]) | ((unsigned)f2b(acc[3]) << 16);
    pk.z = (unsigned)f2b(acc[4]) | ((unsigned)f2b(acc[5]) << 16);
    pk.w = (unsigned)f2b(acc[6]) | ((unsigned)f2b(acc[7]) << 16);
    *(uint4*)cp = pk;
}

template <typename OutT>
__global__ __launch_bounds__(256) void gemm_f32(const float* __restrict__ A,
                                                const float* __restrict__ Bm,
                                                OutT* __restrict__ C,
                                                int M, int N, int K)
{
    __shared__ float As[BKg][BM];
    __shared__ float Bs[BKg][BN];
    int tid = threadIdx.x;
    int ntiles = N / BN;
    int bx = blockIdx.x % ntiles;
    int by = blockIdx.x / ntiles;
    int tm = tid >> 4;          // 0..15
    int tn = tid & 15;          // 0..15

    float acc[8][8] = {};

    int arow = tid >> 1;               // 0..127
    int akof = (tid & 1) * 8;          // 0 or 8
    int bkrow = tid >> 4;              // 0..15
    int bnof = (tid & 15) * 8;         // 0..120

    const float* aptr = A + (size_t)(by * BM + arow) * K + akof;
    const float* bptr = Bm + (size_t)bkrow * N + bx * BN + bnof;

    for (int kt = 0; kt < K; kt += BKg) {
        float4 a0 = *(const float4*)(aptr + kt);
        float4 a1 = *(const float4*)(aptr + kt + 4);
        float4 b0 = *(const float4*)(bptr + (size_t)kt * N);
        float4 b1 = *(const float4*)(bptr + (size_t)kt * N + 4);
        As[akof + 0][arow] = a0.x;
        As[akof + 1][arow] = a0.y;
        As[akof + 2][arow] = a0.z;
        As[akof + 3][arow] = a0.w;
        As[akof + 4][arow] = a1.x;
        As[akof + 5][arow] = a1.y;
        As[akof + 6][arow] = a1.z;
        As[akof + 7][arow] = a1.w;
        *(float4*)&Bs[bkrow][bnof]     = b0;
        *(float4*)&Bs[bkrow][bnof + 4] = b1;
        __syncthreads();
        #pragma unroll
        for (int k = 0; k < BKg; ++k) {
            float a[8], b[8];
            *(float4*)(a)     = *(const float4*)&As[k][tm * 8];
            *(float4*)(a + 4) = *(const float4*)&As[k][tm * 8 + 4];
            *(float4*)(b)     = *(const float4*)&Bs[k][tn * 8];
            *(float4*)(b + 4) = *(const float4*)&Bs[k][tn * 8 + 4];
            #pragma unroll
            for (int i = 0; i < 8; ++i)
                #pragma unroll
                for (int j = 0; j < 8; ++j)
                    acc[i][j] = fmaf(a[i], b[j], acc[i][j]);
        }
        __syncthreads();
    }
    #pragma unroll
    for (int i = 0; i < 8; ++i) {
        int row = by * BM + tm * 8 + i;
        OutT* cp = C + (size_t)row * N + bx * BN + tn * 8;
        storeC8(cp, acc[i]);
    }
}

// ---------------- q/k RMSNorm + partial RoPE, in place on bf16 qkv ws -----------
// grid = B*S*NH*2 blocks of 64 threads. bi: bit0 = (0:q,1:k), bits1-4 = h, bits5-15 = s, bit16 = b
__global__ __launch_bounds__(64) void norm_rope(unsigned short* __restrict__ qkv,
                                                const int* __restrict__ positions,
                                                const float* __restrict__ qw,
                                                const float* __restrict__ kw)
{
    int bi = blockIdx.x;
    int qk = bi & 1;
    int h  = (bi >> 1) & 15;
    int s  = (bi >> 5) & 2047;
    int b  = bi >> 16;
    int d  = threadIdx.x;     // 0..63

    unsigned short* row = qkv + ((size_t)(b * S_ + s)) * NKV + qk * HID + h * HD;
    const float* w = qk ? kw : qw;

    float x0 = b2f(row[d]);
    float x1 = b2f(row[d + 64]);
    float ss = x0 * x0 + x1 * x1;
    #pragma unroll
    for (int off = 32; off > 0; off >>= 1) ss += __shfl_xor(ss, off);
    float inv = rsqrtf(ss * (1.0f / 128.0f) + 1e-6f);
    float n0 = x0 * inv * w[d];
    float n1 = x1 * inv * w[d + 64];

    // rope on dims [0,64): pairs (i, i+32), i = d&31; ang = pos * 10000^(-i/32)
    int i = d & 31;
    float pos = (float)positions[s];
    float ang = pos * exp2f(-(float)i * 0.4152410118609203f);  // log2(1e4)/32
    float cs = cosf(ang), sn = sinf(ang);
    float partner = __shfl_xor(n0, 32);
    float out0 = (d < 32) ? (n0 * cs - partner * sn) : (n0 * cs + partner * sn);
    row[d]      = f2b(out0);
    row[d + 64] = f2b(n1);
}

// ---------------- chunked linear attention scan ----------------
// grid = B*NH*4 blocks (4 e-slices of 32 columns), 256 threads.
// Sequential over NC=32 chunks; state slice [128][32] fp32 in LDS.
__global__ __launch_bounds__(256) void chunk_attn(const unsigned short* __restrict__ qkv,
                                                  const float* __restrict__ rs0,
                                                  float* __restrict__ obuf)
{
    __shared__ unsigned short qs[64][128];
    __shared__ unsigned short ks[64][128];
    __shared__ unsigned short vs[64][32];
    __shared__ unsigned short sc[64][64];
    __shared__ float st[128][32];
    __shared__ float qdec[64];
    __shared__ float kdec[64];

    int bi = blockIdx.x;
    int es = bi & 3;
    int h  = (bi >> 2) & 15;
    int b  = bi >> 6;
    int e0 = es * 32;
    int tid = threadIdx.x;

    // SLOPE[h] = -2^(-0.5*(h+1)) * (1 + 1e-5)
    float slope = -exp2f(-0.5f * (float)(h + 1)) * (1.0f + 1e-5f);
    float lam = expf(slope * 64.0f);

    if (tid < 64) {
        qdec[tid] = expf(slope * (float)(tid + 1));
        kdec[tid] = expf(slope * (float)(63 - tid));
    }
    const float* rsp = rs0 + ((size_t)(b * NH + h)) * HD * HD + e0;
    for (int idx = tid; idx < 128 * 32; idx += 256) {
        int d = idx >> 5, e = idx & 31;
        st[d][e] = rsp[(size_t)d * HD + e];
    }
    __syncthreads();

    const unsigned short* qbase = qkv + (size_t)b * S_ * NKV + h * HD;
    float* obase = obuf + (size_t)b * S_ * 2048 + h * HD + e0;

    int i0  = (tid >> 4) * 4;   // o phase: 4 rows
    int eo  = (tid & 15) * 2;   //          2 e-cols
    int sd0 = (tid >> 3) * 4;   // state phase: 4 d-rows
    int se0 = (tid & 7) * 4;    //              4 e-cols

    for (int cc = 0; cc < NC; ++cc) {
        const unsigned short* crow = qbase + (size_t)cc * CHUNK_ * NKV;
        // ---- stage q,k (64x128) and v slice (64x32) ----
        for (int idx = tid; idx < 8192; idx += 256) {
            int i = idx >> 7, d = idx & 127;
            size_t off = (size_t)i * NKV + d;
            qs[i][d] = crow[off];
            ks[i][d] = crow[off + HID];
        }
        for (int idx = tid; idx < 2048; idx += 256) {
            int i = idx >> 5, e = idx & 31;
            vs[i][e] = crow[(size_t)i * NKV + 2 * HID + e0 + e];
        }
        __syncthreads();

        // ---- scores: sc[i][j] = (q_i . k_j) * mask ----
        {
            int si0 = (tid >> 4) * 4, sj0 = (tid & 15) * 4;
            float acc[4][4] = {};
            for (int d0 = 0; d0 < 128; d0 += 4) {
                float qv[4][4], kv[4][4];
                #pragma unroll
                for (int r = 0; r < 4; ++r) {
                    uint2 qu = *(const uint2*)&qs[si0 + r][d0];
                    qv[r][0] = b2f(qu.x); qv[r][1] = b2f(qu.x >> 16);
                    qv[r][2] = b2f(qu.y); qv[r][3] = b2f(qu.y >> 16);
                    uint2 ku = *(const uint2*)&ks[sj0 + r][d0];
                    kv[r][0] = b2f(ku.x); kv[r][1] = b2f(ku.x >> 16);
                    kv[r][2] = b2f(ku.y); kv[r][3] = b2f(ku.y >> 16);
                }
                #pragma unroll
                for (int r = 0; r < 4; ++r)
                    #pragma unroll
                    for (int c2 = 0; c2 < 4; ++c2)
                        #pragma unroll
                        for (int dd = 0; dd < 4; ++dd)
                            acc[r][c2] = fmaf(qv[r][dd], kv[c2][dd], acc[r][c2]);
            }
            #pragma unroll
            for (int r = 0; r < 4; ++r)
                #pragma unroll
                for (int c2 = 0; c2 < 4; ++c2) {
                    int ii = si0 + r, jj = sj0 + c2;
                    float v = (ii >= jj) ? acc[r][c2] * expf(slope * (float)(ii - jj)) : 0.0f;
                    sc[ii][jj] = f2b(v);
                }
        }
        __syncthreads();

        // ---- o accumulators (intra + inter, reads OLD state) ----
        float oacc[4][2] = {};
        float eacc[4][2] = {};
        for (int j = 0; j < 64; j += 2) {
            unsigned int v0 = *(const unsigned int*)&vs[j][eo];
            unsigned int v1 = *(const unsigned int*)&vs[j + 1][eo];
            float v00 = b2f(v0), v01 = b2f(v0 >> 16);
            float v10 = b2f(v1), v11 = b2f(v1 >> 16);
            #pragma unroll
            for (int r = 0; r < 4; ++r) {
                unsigned int su = *(const unsigned int*)&sc[i0 + r][j];
                float s0 = b2f(su), s1 = b2f(su >> 16);
                oacc[r][0] += s0 * v00 + s1 * v10;
                oacc[r][1] += s0 * v01 + s1 * v11;
            }
        }
        for (int d = 0; d < 128; d += 2) {
            float2 t0 = *(const float2*)&st[d][eo];
            float2 t1 = *(const float2*)&st[d + 1][eo];
            #pragma unroll
            for (int r = 0; r < 4; ++r) {
                unsigned int qu = *(const unsigned int*)&qs[i0 + r][d];
                float q0 = b2f(qu), q1 = b2f(qu >> 16);
                eacc[r][0] += q0 * t0.x + q1 * t1.x;
                eacc[r][1] += q0 * t0.y + q1 * t1.y;
            }
        }
        // ---- state accumulator (no state writes yet) ----
        float sacc[4][4] = {};
        for (int j = 0; j < 64; ++j) {
            float kd = kdec[j];
            uint2 ku = *(const uint2*)&ks[j][sd0];
            float k0 = b2f(ku.x), k1 = b2f(ku.x >> 16);
            float k2 = b2f(ku.y), k3 = b2f(ku.y >> 16);
            uint2 vu = *(const uint2*)&vs[j][se0];
            float w0 = b2f(vu.x) * kd, w1 = b2f(vu.x >> 16) * kd;
            float w2 = b2f(vu.y) * kd, w3 = b2f(vu.y >> 16) * kd;
            sacc[0][0] += k0 * w0; sacc[0][1] += k0 * w1; sacc[0][2] += k0 * w2; sacc[0][3] += k0 * w3;
            sacc[1][0] += k1 * w0; sacc[1][1] += k1 * w1; sacc[1][2] += k1 * w2; sacc[1][3] += k1 * w3;
            sacc[2][0] += k2 * w0; sacc[2][1] += k2 * w1; sacc[2][2] += k2 * w2; sacc[2][3] += k2 * w3;
            sacc[3][0] += k3 * w0; sacc[3][1] += k3 * w1; sacc[3][2] += k3 * w2; sacc[3][3] += k3 * w3;
        }
        __syncthreads();   // all old-state reads done
        #pragma unroll
        for (int dd = 0; dd < 4; ++dd)
            #pragma unroll
            for (int ee = 0; ee < 4; ++ee)
                st[sd0 + dd][se0 + ee] = st[sd0 + dd][se0 + ee] * lam + sacc[dd][ee];
        #pragma unroll
        for (int r = 0; r < 4; ++r) {
            float qd = qdec[i0 + r];
            float o0 = oacc[r][0] + qd * eacc[r][0];
            float o1 = oacc[r][1] + qd * eacc[r][1];
            *(float2*)(obase + (size_t)(cc * CHUNK_ + i0 + r) * 2048 + eo) = make_float2(o0, o1);
        }
        // next iteration's staging barrier orders st writes vs next o_inter reads
    }
}

// ---------------- group RMSNorm + sigmoid gate (into gate buffer, fp32) ----------
// grid = B*S*GROUPS blocks of 256 (one group of 256 cols per block)
__global__ __launch_bounds__(256) void gnorm_gate(const float* __restrict__ o,
                                                  float* __restrict__ gate,
                                                  const float* __restrict__ gw)
{
    int row = blockIdx.x >> 3;
    int g   = blockIdx.x & 7;
    int col = g * 256 + threadIdx.x;
    size_t idx = (size_t)row * 2048 + col;
    float ov = o[idx];
    float ss = ov * ov;
    #pragma unroll
    for (int off = 32; off > 0; off >>= 1) ss += __shfl_xor(ss, off);
    __shared__ float part[4];
    if ((threadIdx.x & 63) == 0) part[threadIdx.x >> 6] = ss;
    __syncthreads();
    float tot = part[0] + part[1] + part[2] + part[3];
    float inv = rsqrtf(tot * (1.0f / 256.0f) + 1e-6f);
    float gv = gate[idx];
    float sig = 1.0f / (1.0f + expf(-gv));
    gate[idx] = ov * inv * gw[col] * sig;
}

// ---------------- launch ----------------
extern "C" void kernel_launch(void* const* d_in, const int* in_sizes, int n_in,
                              void* d_out, int out_size, void* d_ws, size_t ws_size,
                              hipStream_t stream) {
    const int*   positions = (const int*)d_in[0];
    const float* hidden    = (const float*)d_in[1];
    const float* rstate    = (const float*)d_in[2];
    const float* w_qkv     = (const float*)d_in[3];
    const float* w_g       = (const float*)d_in[4];
    const float* w_dense   = (const float*)d_in[5];
    const float* q_norm_w  = (const float*)d_in[6];
    const float* k_norm_w  = (const float*)d_in[7];
    const float* g_norm_w  = (const float*)d_in[8];
    float* out = (float*)d_out;

    unsigned short* qkv = (unsigned short*)d_ws;                     // 4096*6144 bf16 = 50.3 MB
    float* obuf = (float*)(qkv + (size_t)4096 * 6144);               // 4096*2048 f32  = 33.6 MB
    float* gbuf = obuf + (size_t)4096 * 2048;                        // 4096*2048 f32  = 33.6 MB

    const int MR = B_ * S_;  // 4096

    // qkv projection (fp32 inputs -> bf16 ws)
    gemm_f32<unsigned short><<<dim3((MR / BM) * (NKV / BN)), dim3(256), 0, stream>>>(hidden, w_qkv, qkv, MR, NKV, HID);
    // q/k norm + rope (in place on bf16 qkv)
    norm_rope<<<dim3(B_ * S_ * NH * 2), dim3(64), 0, stream>>>(qkv, positions, q_norm_w, k_norm_w);
    // gate projection (fp32 -> fp32)
    gemm_f32<float><<<dim3((MR / BM) * (HID / BN)), dim3(256), 0, stream>>>(hidden, w_g, gbuf, MR, HID, HID);
    // chunked scan (bf16 q/k/v, fp32 state, fp32 o)
    chunk_attn<<<dim3(B_ * NH * 4), dim3(256), 0, stream>>>(qkv, rstate, obuf);
    // group norm + gate (writes gated activations into gbuf)
    gnorm_gate<<<dim3(MR * GROUPS_), dim3(256), 0, stream>>>(obuf, gbuf, g_norm_w);
    // output projection (fp32 -> fp32 out)
    gemm_f32<float><<<dim3((MR / BM) * (HID / BN)), dim3(256), 0, stream>>>(gbuf, w_dense, out, MR, HID, HID);
}

// Round 3
// 1319.520 us; speedup vs baseline: 2.3668x; 2.3668x over previous
//
#include <hip/hip_runtime.h>
#include <hip/hip_bf16.h>
#include <math.h>

// ---- problem constants ----
#define NH   16
#define HD   128
#define HID  2048
#define NKV  6144      // 3*NH*HD
#define B_   2
#define S_   2048
#define NC   32        // S/CHUNK
#define CHUNK_ 64
#define GROUPS_ 8

typedef __bf16 bf16_t;
typedef bf16_t bf16x8 __attribute__((ext_vector_type(8)));
typedef float  f32x4  __attribute__((ext_vector_type(4)));

__device__ __forceinline__ float b2f(unsigned int u) {
    union { unsigned int u; float f; } c; c.u = (u & 0xffffu) << 16; return c.f;
}
__device__ __forceinline__ unsigned int f2b(float f) {
    union { float f; unsigned int u; } c; c.f = f;
    unsigned int u = c.u;
    return (u + 0x7fffu + ((u >> 16) & 1u)) >> 16;
}

#define GLOAD_LDS16(gp, lp) __builtin_amdgcn_global_load_lds(                     \
    (const __attribute__((address_space(1))) void*)(gp),                          \
    (__attribute__((address_space(3))) void*)(lp), 16, 0, 0)

// ---------------- fp32 -> bf16 elementwise (8 elems/thread) ----------------
__global__ __launch_bounds__(256) void cvt_bf16(const float* __restrict__ in,
                                                unsigned short* __restrict__ out, int n8)
{
    int i = blockIdx.x * 256 + threadIdx.x;
    if (i >= n8) return;
    const float4* p = (const float4*)in + (size_t)i * 2;
    float4 a = p[0], b = p[1];
    uint4 o;
    o.x = f2b(a.x) | (f2b(a.y) << 16);
    o.y = f2b(a.z) | (f2b(a.w) << 16);
    o.z = f2b(b.x) | (f2b(b.y) << 16);
    o.w = f2b(b.z) | (f2b(b.w) << 16);
    ((uint4*)out)[i] = o;
}

// ------------- fp32 [K][N] -> bf16 [N][K] transpose (32x32 tiles) ---------------
__global__ __launch_bounds__(256) void transpose_cvt(const float* __restrict__ in,
                                                     unsigned short* __restrict__ out,
                                                     int Kdim, int Ndim)
{
    __shared__ float tile[32][33];
    int ntx = Ndim >> 5;
    int bx = blockIdx.x % ntx;           // col tile (N)
    int by = blockIdx.x / ntx;           // row tile (K)
    int lx = threadIdx.x & 31, ly = threadIdx.x >> 5;   // ly 0..7
    int r0 = by * 32, c0 = bx * 32;
    #pragma unroll
    for (int r = 0; r < 4; ++r)
        tile[ly + r * 8][lx] = in[(size_t)(r0 + ly + r * 8) * Ndim + c0 + lx];
    __syncthreads();
    #pragma unroll
    for (int r = 0; r < 4; ++r)
        out[(size_t)(c0 + ly + r * 8) * Kdim + r0 + lx] = (unsigned short)f2b(tile[lx][ly + r * 8]);
}

// ---------------- MFMA GEMM: C[M,N] = A[M,K] @ Bt[N,K]^T ----------------
// bf16 in, fp32 acc, OutT out. 128x128 tile, BK=32, 256 thr (4 waves, 64x64 each).
__device__ __forceinline__ void storeOne(float* p, float v) { *p = v; }
__device__ __forceinline__ void storeOne(unsigned short* p, float v) { *p = (unsigned short)f2b(v); }

template <typename OutT>
__global__ __launch_bounds__(256) void gemm_mfma(const bf16_t* __restrict__ A,   // [M][K]
                                                 const bf16_t* __restrict__ Bt,  // [N][K]
                                                 OutT* __restrict__ C,           // [M][N]
                                                 int M, int N, int K)
{
    __shared__ bf16_t As[128 * 32];
    __shared__ bf16_t Bs[128 * 32];
    int tid  = threadIdx.x;
    int ntiles = N >> 7;
    int bx = blockIdx.x % ntiles;
    int by = blockIdx.x / ntiles;
    int lane = tid & 63;
    int wave = tid >> 6;
    int wm = (wave >> 1) * 64;
    int wn = (wave & 1) * 64;
    int l16  = lane & 15;
    int quad = lane >> 4;

    f32x4 acc[4][4];
    #pragma unroll
    for (int i = 0; i < 4; ++i)
        #pragma unroll
        for (int j = 0; j < 4; ++j) { f32x4 z = {0.f, 0.f, 0.f, 0.f}; acc[i][j] = z; }

    // staging: thread t covers tile elems [t*8, t*8+8): row = t>>2 (0..63), col = (t&3)*8
    const bf16_t* aG = A  + (size_t)(by * 128 + (tid >> 2)) * K + (tid & 3) * 8;
    const bf16_t* bG = Bt + (size_t)(bx * 128 + (tid >> 2)) * K + (tid & 3) * 8;
    bf16_t* aL0 = As + tid * 8;
    bf16_t* aL1 = As + 2048 + tid * 8;
    bf16_t* bL0 = Bs + tid * 8;
    bf16_t* bL1 = Bs + 2048 + tid * 8;
    const size_t half = (size_t)64 * K;

    for (int kt = 0; kt < K; kt += 32) {
        GLOAD_LDS16(aG + kt,        aL0);
        GLOAD_LDS16(aG + half + kt, aL1);
        GLOAD_LDS16(bG + kt,        bL0);
        GLOAD_LDS16(bG + half + kt, bL1);
        __syncthreads();
        bf16x8 af[4], bf[4];
        #pragma unroll
        for (int t = 0; t < 4; ++t) {
            af[t] = *(const bf16x8*)(As + (wm + t * 16 + l16) * 32 + quad * 8);
            bf[t] = *(const bf16x8*)(Bs + (wn + t * 16 + l16) * 32 + quad * 8);
        }
        #pragma unroll
        for (int mt = 0; mt < 4; ++mt)
            #pragma unroll
            for (int nt = 0; nt < 4; ++nt)
                acc[mt][nt] = __builtin_amdgcn_mfma_f32_16x16x32_bf16(af[mt], bf[nt], acc[mt][nt], 0, 0, 0);
        __syncthreads();
    }

    #pragma unroll
    for (int mt = 0; mt < 4; ++mt)
        #pragma unroll
        for (int nt = 0; nt < 4; ++nt) {
            int col = bx * 128 + wn + nt * 16 + l16;
            #pragma unroll
            for (int r = 0; r < 4; ++r) {
                int row = by * 128 + wm + mt * 16 + quad * 4 + r;
                storeOne(C + (size_t)row * N + col, acc[mt][nt][r]);
            }
        }
}

// ---------------- q/k RMSNorm + partial RoPE, in place on bf16 qkv ws -----------
// grid = B*S*NH*2 blocks of 64 threads. bi: bit0 = (0:q,1:k), bits1-4 = h, bits5-15 = s, bit16 = b
__global__ __launch_bounds__(64) void norm_rope(unsigned short* __restrict__ qkv,
                                                const int* __restrict__ positions,
                                                const float* __restrict__ qw,
                                                const float* __restrict__ kw)
{
    int bi = blockIdx.x;
    int qk = bi & 1;
    int h  = (bi >> 1) & 15;
    int s  = (bi >> 5) & 2047;
    int b  = bi >> 16;
    int d  = threadIdx.x;     // 0..63

    unsigned short* row = qkv + ((size_t)(b * S_ + s)) * NKV + qk * HID + h * HD;
    const float* w = qk ? kw : qw;

    float x0 = b2f(row[d]);
    float x1 = b2f(row[d + 64]);
    float ss = x0 * x0 + x1 * x1;
    #pragma unroll
    for (int off = 32; off > 0; off >>= 1) ss += __shfl_xor(ss, off);
    float inv = rsqrtf(ss * (1.0f / 128.0f) + 1e-6f);
    float n0 = x0 * inv * w[d];
    float n1 = x1 * inv * w[d + 64];

    // rope on dims [0,64): pairs (i, i+32), i = d&31; ang = pos * 10000^(-i/32)
    int i = d & 31;
    float pos = (float)positions[s];
    float ang = pos * exp2f(-(float)i * 0.4152410118609203f);  // log2(1e4)/32
    float cs = cosf(ang), sn = sinf(ang);
    float partner = __shfl_xor(n0, 32);
    float out0 = (d < 32) ? (n0 * cs - partner * sn) : (n0 * cs + partner * sn);
    row[d]      = (unsigned short)f2b(out0);
    row[d + 64] = (unsigned short)f2b(n1);
}

// ---------------- chunked linear attention scan ----------------
// grid = B*NH*4 blocks (4 e-slices of 32 columns), 256 threads.
__global__ __launch_bounds__(256) void chunk_attn(const unsigned short* __restrict__ qkv,
                                                  const float* __restrict__ rs0,
                                                  float* __restrict__ obuf)
{
    __shared__ unsigned short qs[64][128];
    __shared__ unsigned short ks[64][128];
    __shared__ unsigned short vs[64][32];
    __shared__ unsigned short sc[64][64];
    __shared__ float st[128][32];
    __shared__ float qdec[64];
    __shared__ float kdec[64];

    int bi = blockIdx.x;
    int es = bi & 3;
    int h  = (bi >> 2) & 15;
    int b  = bi >> 6;
    int e0 = es * 32;
    int tid = threadIdx.x;

    float slope = -exp2f(-0.5f * (float)(h + 1)) * (1.0f + 1e-5f);
    float lam = expf(slope * 64.0f);

    if (tid < 64) {
        qdec[tid] = expf(slope * (float)(tid + 1));
        kdec[tid] = expf(slope * (float)(63 - tid));
    }
    const float* rsp = rs0 + ((size_t)(b * NH + h)) * HD * HD + e0;
    for (int idx = tid; idx < 128 * 32; idx += 256) {
        int d = idx >> 5, e = idx & 31;
        st[d][e] = rsp[(size_t)d * HD + e];
    }
    __syncthreads();

    const unsigned short* qbase = qkv + (size_t)b * S_ * NKV + h * HD;
    float* obase = obuf + (size_t)b * S_ * 2048 + h * HD + e0;

    int i0  = (tid >> 4) * 4;
    int eo  = (tid & 15) * 2;
    int sd0 = (tid >> 3) * 4;
    int se0 = (tid & 7) * 4;

    for (int cc = 0; cc < NC; ++cc) {
        const unsigned short* crow = qbase + (size_t)cc * CHUNK_ * NKV;
        for (int idx = tid; idx < 8192; idx += 256) {
            int i = idx >> 7, d = idx & 127;
            size_t off = (size_t)i * NKV + d;
            qs[i][d] = crow[off];
            ks[i][d] = crow[off + HID];
        }
        for (int idx = tid; idx < 2048; idx += 256) {
            int i = idx >> 5, e = idx & 31;
            vs[i][e] = crow[(size_t)i * NKV + 2 * HID + e0 + e];
        }
        __syncthreads();

        {
            int si0 = (tid >> 4) * 4, sj0 = (tid & 15) * 4;
            float acc[4][4] = {};
            for (int d0 = 0; d0 < 128; d0 += 4) {
                float qv[4][4], kv[4][4];
                #pragma unroll
                for (int r = 0; r < 4; ++r) {
                    uint2 qu = *(const uint2*)&qs[si0 + r][d0];
                    qv[r][0] = b2f(qu.x); qv[r][1] = b2f(qu.x >> 16);
                    qv[r][2] = b2f(qu.y); qv[r][3] = b2f(qu.y >> 16);
                    uint2 ku = *(const uint2*)&ks[sj0 + r][d0];
                    kv[r][0] = b2f(ku.x); kv[r][1] = b2f(ku.x >> 16);
                    kv[r][2] = b2f(ku.y); kv[r][3] = b2f(ku.y >> 16);
                }
                #pragma unroll
                for (int r = 0; r < 4; ++r)
                    #pragma unroll
                    for (int c2 = 0; c2 < 4; ++c2)
                        #pragma unroll
                        for (int dd = 0; dd < 4; ++dd)
                            acc[r][c2] = fmaf(qv[r][dd], kv[c2][dd], acc[r][c2]);
            }
            #pragma unroll
            for (int r = 0; r < 4; ++r)
                #pragma unroll
                for (int c2 = 0; c2 < 4; ++c2) {
                    int ii = si0 + r, jj = sj0 + c2;
                    float v = (ii >= jj) ? acc[r][c2] * expf(slope * (float)(ii - jj)) : 0.0f;
                    sc[ii][jj] = (unsigned short)f2b(v);
                }
        }
        __syncthreads();

        float oacc[4][2] = {};
        float eacc[4][2] = {};
        for (int j = 0; j < 64; j += 2) {
            unsigned int v0 = *(const unsigned int*)&vs[j][eo];
            unsigned int v1 = *(const unsigned int*)&vs[j + 1][eo];
            float v00 = b2f(v0), v01 = b2f(v0 >> 16);
            float v10 = b2f(v1), v11 = b2f(v1 >> 16);
            #pragma unroll
            for (int r = 0; r < 4; ++r) {
                unsigned int su = *(const unsigned int*)&sc[i0 + r][j];
                float s0 = b2f(su), s1 = b2f(su >> 16);
                oacc[r][0] += s0 * v00 + s1 * v10;
                oacc[r][1] += s0 * v01 + s1 * v11;
            }
        }
        for (int d = 0; d < 128; d += 2) {
            float2 t0 = *(const float2*)&st[d][eo];
            float2 t1 = *(const float2*)&st[d + 1][eo];
            #pragma unroll
            for (int r = 0; r < 4; ++r) {
                unsigned int qu = *(const unsigned int*)&qs[i0 + r][d];
                float q0 = b2f(qu), q1 = b2f(qu >> 16);
                eacc[r][0] += q0 * t0.x + q1 * t1.x;
                eacc[r][1] += q0 * t0.y + q1 * t1.y;
            }
        }
        float sacc[4][4] = {};
        for (int j = 0; j < 64; ++j) {
            float kd = kdec[j];
            uint2 ku = *(const uint2*)&ks[j][sd0];
            float k0 = b2f(ku.x), k1 = b2f(ku.x >> 16);
            float k2 = b2f(ku.y), k3 = b2f(ku.y >> 16);
            uint2 vu = *(const uint2*)&vs[j][se0];
            float w0 = b2f(vu.x) * kd, w1 = b2f(vu.x >> 16) * kd;
            float w2 = b2f(vu.y) * kd, w3 = b2f(vu.y >> 16) * kd;
            sacc[0][0] += k0 * w0; sacc[0][1] += k0 * w1; sacc[0][2] += k0 * w2; sacc[0][3] += k0 * w3;
            sacc[1][0] += k1 * w0; sacc[1][1] += k1 * w1; sacc[1][2] += k1 * w2; sacc[1][3] += k1 * w3;
            sacc[2][0] += k2 * w0; sacc[2][1] += k2 * w1; sacc[2][2] += k2 * w2; sacc[2][3] += k2 * w3;
            sacc[3][0] += k3 * w0; sacc[3][1] += k3 * w1; sacc[3][2] += k3 * w2; sacc[3][3] += k3 * w3;
        }
        __syncthreads();
        #pragma unroll
        for (int dd = 0; dd < 4; ++dd)
            #pragma unroll
            for (int ee = 0; ee < 4; ++ee)
                st[sd0 + dd][se0 + ee] = st[sd0 + dd][se0 + ee] * lam + sacc[dd][ee];
        #pragma unroll
        for (int r = 0; r < 4; ++r) {
            float qd = qdec[i0 + r];
            float o0 = oacc[r][0] + qd * eacc[r][0];
            float o1 = oacc[r][1] + qd * eacc[r][1];
            *(float2*)(obase + (size_t)(cc * CHUNK_ + i0 + r) * 2048 + eo) = make_float2(o0, o1);
        }
    }
}

// ------- group RMSNorm + sigmoid gate: read o fp32 + gate bf16, write bf16 -------
__global__ __launch_bounds__(256) void gnorm_gate(const float* __restrict__ o,
                                                  unsigned short* __restrict__ gate,
                                                  const float* __restrict__ gw)
{
    int row = blockIdx.x >> 3;
    int g   = blockIdx.x & 7;
    int col = g * 256 + threadIdx.x;
    size_t idx = (size_t)row * 2048 + col;
    float ov = o[idx];
    float ss = ov * ov;
    #pragma unroll
    for (int off = 32; off > 0; off >>= 1) ss += __shfl_xor(ss, off);
    __shared__ float part[4];
    if ((threadIdx.x & 63) == 0) part[threadIdx.x >> 6] = ss;
    __syncthreads();
    float tot = part[0] + part[1] + part[2] + part[3];
    float inv = rsqrtf(tot * (1.0f / 256.0f) + 1e-6f);
    float gv = b2f(gate[idx]);
    float sig = 1.0f / (1.0f + expf(-gv));
    gate[idx] = (unsigned short)f2b(ov * inv * gw[col] * sig);
}

// ---------------- launch ----------------
extern "C" void kernel_launch(void* const* d_in, const int* in_sizes, int n_in,
                              void* d_out, int out_size, void* d_ws, size_t ws_size,
                              hipStream_t stream) {
    const int*   positions = (const int*)d_in[0];
    const float* hidden    = (const float*)d_in[1];
    const float* rstate    = (const float*)d_in[2];
    const float* w_qkv     = (const float*)d_in[3];
    const float* w_g       = (const float*)d_in[4];
    const float* w_dense   = (const float*)d_in[5];
    const float* q_norm_w  = (const float*)d_in[6];
    const float* k_norm_w  = (const float*)d_in[7];
    const float* g_norm_w  = (const float*)d_in[8];
    float* out = (float*)d_out;

    const int MR = B_ * S_;  // 4096

    // ---- ws layout (bytes) ----
    char* w = (char*)d_ws;
    unsigned short* qkv  = (unsigned short*)w;            w += (size_t)MR * NKV * 2;     // 50.3 MB
    float*          obuf = (float*)w;                     w += (size_t)MR * 2048 * 4;    // 33.6 MB
    unsigned short* gbuf = (unsigned short*)w;            w += (size_t)MR * 2048 * 2;    // 16.8 MB
    unsigned short* hbf  = (unsigned short*)w;            w += (size_t)MR * HID * 2;     // 16.8 MB
    unsigned short* wqT  = (unsigned short*)w;            w += (size_t)NKV * HID * 2;    // 25.2 MB
    unsigned short* wgT  = (unsigned short*)w;            w += (size_t)HID * HID * 2;    // 8.4 MB
    unsigned short* wdT  = (unsigned short*)w;            w += (size_t)HID * HID * 2;    // 8.4 MB

    // ---- conversions ----
    cvt_bf16<<<dim3((MR * HID / 8 + 255) / 256), dim3(256), 0, stream>>>(hidden, hbf, MR * HID / 8);
    transpose_cvt<<<dim3((HID / 32) * (NKV / 32)), dim3(256), 0, stream>>>(w_qkv, wqT, HID, NKV);
    transpose_cvt<<<dim3((HID / 32) * (HID / 32)), dim3(256), 0, stream>>>(w_g, wgT, HID, HID);
    transpose_cvt<<<dim3((HID / 32) * (HID / 32)), dim3(256), 0, stream>>>(w_dense, wdT, HID, HID);

    // ---- qkv projection (bf16 MFMA) ----
    gemm_mfma<unsigned short><<<dim3((MR / 128) * (NKV / 128)), dim3(256), 0, stream>>>(
        (const bf16_t*)hbf, (const bf16_t*)wqT, qkv, MR, NKV, HID);
    // ---- q/k norm + rope (in place on bf16 qkv) ----
    norm_rope<<<dim3(B_ * S_ * NH * 2), dim3(64), 0, stream>>>(qkv, positions, q_norm_w, k_norm_w);
    // ---- gate projection ----
    gemm_mfma<unsigned short><<<dim3((MR / 128) * (HID / 128)), dim3(256), 0, stream>>>(
        (const bf16_t*)hbf, (const bf16_t*)wgT, gbuf, MR, HID, HID);
    // ---- chunked scan ----
    chunk_attn<<<dim3(B_ * NH * 4), dim3(256), 0, stream>>>(qkv, rstate, obuf);
    // ---- group norm + gate (bf16 gated activations into gbuf) ----
    gnorm_gate<<<dim3(MR * GROUPS_), dim3(256), 0, stream>>>(obuf, gbuf, g_norm_w);
    // ---- output projection (fp32 out) ----
    gemm_mfma<float><<<dim3((MR / 128) * (HID / 128)), dim3(256), 0, stream>>>(
        (const bf16_t*)gbuf, (const bf16_t*)wdT, out, MR, HID, HID);
}

// Round 4
// 519.709 us; speedup vs baseline: 6.0091x; 2.5390x over previous
//
#include <hip/hip_runtime.h>
#include <hip/hip_bf16.h>
#include <math.h>

// ---- problem constants ----
#define NH   16
#define HD   128
#define HID  2048
#define NKV  6144      // 3*NH*HD
#define B_   2
#define S_   2048
#define NC   32        // S/CHUNK
#define CHUNK_ 64
#define GROUPS_ 8

typedef __bf16 bf16_t;
typedef bf16_t bf16x8 __attribute__((ext_vector_type(8)));
typedef float  f32x4  __attribute__((ext_vector_type(4)));

__device__ __forceinline__ float b2f(unsigned int u) {
    union { unsigned int u; float f; } c; c.u = (u & 0xffffu) << 16; return c.f;
}
__device__ __forceinline__ unsigned int f2b(float f) {
    union { float f; unsigned int u; } c; c.f = f;
    unsigned int u = c.u;
    return (u + 0x7fffu + ((u >> 16) & 1u)) >> 16;
}

#define GLOAD_LDS16(gp, lp) __builtin_amdgcn_global_load_lds(                     \
    (const __attribute__((address_space(1))) void*)(gp),                          \
    (__attribute__((address_space(3))) void*)(lp), 16, 0, 0)

// ---------------- fp32 -> bf16 elementwise (8 elems/thread) ----------------
__global__ __launch_bounds__(256) void cvt_bf16(const float* __restrict__ in,
                                                unsigned short* __restrict__ out, int n8)
{
    int i = blockIdx.x * 256 + threadIdx.x;
    if (i >= n8) return;
    const float4* p = (const float4*)in + (size_t)i * 2;
    float4 a = p[0], b = p[1];
    uint4 o;
    o.x = f2b(a.x) | (f2b(a.y) << 16);
    o.y = f2b(a.z) | (f2b(a.w) << 16);
    o.z = f2b(b.x) | (f2b(b.y) << 16);
    o.w = f2b(b.z) | (f2b(b.w) << 16);
    ((uint4*)out)[i] = o;
}

// ------------- fp32 [K][N] -> bf16 [N][K] transpose (32x32 tiles) ---------------
__global__ __launch_bounds__(256) void transpose_cvt(const float* __restrict__ in,
                                                     unsigned short* __restrict__ out,
                                                     int Kdim, int Ndim)
{
    __shared__ float tile[32][33];
    int ntx = Ndim >> 5;
    int bx = blockIdx.x % ntx;
    int by = blockIdx.x / ntx;
    int lx = threadIdx.x & 31, ly = threadIdx.x >> 5;
    int r0 = by * 32, c0 = bx * 32;
    #pragma unroll
    for (int r = 0; r < 4; ++r)
        tile[ly + r * 8][lx] = in[(size_t)(r0 + ly + r * 8) * Ndim + c0 + lx];
    __syncthreads();
    #pragma unroll
    for (int r = 0; r < 4; ++r)
        out[(size_t)(c0 + ly + r * 8) * Kdim + r0 + lx] = (unsigned short)f2b(tile[lx][ly + r * 8]);
}

// ---------------- MFMA GEMM: C[M,N] = A[M,K] @ Bt[N,K]^T ----------------
__device__ __forceinline__ void storeOne(float* p, float v) { *p = v; }
__device__ __forceinline__ void storeOne(unsigned short* p, float v) { *p = (unsigned short)f2b(v); }

template <typename OutT>
__global__ __launch_bounds__(256) void gemm_mfma(const bf16_t* __restrict__ A,   // [M][K]
                                                 const bf16_t* __restrict__ Bt,  // [N][K]
                                                 OutT* __restrict__ C,           // [M][N]
                                                 int M, int N, int K)
{
    __shared__ bf16_t As[128 * 32];
    __shared__ bf16_t Bs[128 * 32];
    int tid  = threadIdx.x;
    int ntiles = N >> 7;
    int bx = blockIdx.x % ntiles;
    int by = blockIdx.x / ntiles;
    int lane = tid & 63;
    int wave = tid >> 6;
    int wm = (wave >> 1) * 64;
    int wn = (wave & 1) * 64;
    int l16  = lane & 15;
    int quad = lane >> 4;

    f32x4 acc[4][4];
    #pragma unroll
    for (int i = 0; i < 4; ++i)
        #pragma unroll
        for (int j = 0; j < 4; ++j) { f32x4 z = {0.f, 0.f, 0.f, 0.f}; acc[i][j] = z; }

    const bf16_t* aG = A  + (size_t)(by * 128 + (tid >> 2)) * K + (tid & 3) * 8;
    const bf16_t* bG = Bt + (size_t)(bx * 128 + (tid >> 2)) * K + (tid & 3) * 8;
    bf16_t* aL0 = As + tid * 8;
    bf16_t* aL1 = As + 2048 + tid * 8;
    bf16_t* bL0 = Bs + tid * 8;
    bf16_t* bL1 = Bs + 2048 + tid * 8;
    const size_t half = (size_t)64 * K;

    for (int kt = 0; kt < K; kt += 32) {
        GLOAD_LDS16(aG + kt,        aL0);
        GLOAD_LDS16(aG + half + kt, aL1);
        GLOAD_LDS16(bG + kt,        bL0);
        GLOAD_LDS16(bG + half + kt, bL1);
        __syncthreads();
        bf16x8 af[4], bf[4];
        #pragma unroll
        for (int t = 0; t < 4; ++t) {
            af[t] = *(const bf16x8*)(As + (wm + t * 16 + l16) * 32 + quad * 8);
            bf[t] = *(const bf16x8*)(Bs + (wn + t * 16 + l16) * 32 + quad * 8);
        }
        #pragma unroll
        for (int mt = 0; mt < 4; ++mt)
            #pragma unroll
            for (int nt = 0; nt < 4; ++nt)
                acc[mt][nt] = __builtin_amdgcn_mfma_f32_16x16x32_bf16(af[mt], bf[nt], acc[mt][nt], 0, 0, 0);
        __syncthreads();
    }

    #pragma unroll
    for (int mt = 0; mt < 4; ++mt)
        #pragma unroll
        for (int nt = 0; nt < 4; ++nt) {
            int col = bx * 128 + wn + nt * 16 + l16;
            #pragma unroll
            for (int r = 0; r < 4; ++r) {
                int row = by * 128 + wm + mt * 16 + quad * 4 + r;
                storeOne(C + (size_t)row * N + col, acc[mt][nt][r]);
            }
        }
}

// ---------------- q/k RMSNorm + partial RoPE, in place on bf16 qkv ws -----------
__global__ __launch_bounds__(64) void norm_rope(unsigned short* __restrict__ qkv,
                                                const int* __restrict__ positions,
                                                const float* __restrict__ qw,
                                                const float* __restrict__ kw)
{
    int bi = blockIdx.x;
    int qk = bi & 1;
    int h  = (bi >> 1) & 15;
    int s  = (bi >> 5) & 2047;
    int b  = bi >> 16;
    int d  = threadIdx.x;

    unsigned short* row = qkv + ((size_t)(b * S_ + s)) * NKV + qk * HID + h * HD;
    const float* w = qk ? kw : qw;

    float x0 = b2f(row[d]);
    float x1 = b2f(row[d + 64]);
    float ss = x0 * x0 + x1 * x1;
    #pragma unroll
    for (int off = 32; off > 0; off >>= 1) ss += __shfl_xor(ss, off);
    float inv = rsqrtf(ss * (1.0f / 128.0f) + 1e-6f);
    float n0 = x0 * inv * w[d];
    float n1 = x1 * inv * w[d + 64];

    int i = d & 31;
    float pos = (float)positions[s];
    float ang = pos * exp2f(-(float)i * 0.4152410118609203f);
    float cs = cosf(ang), sn = sinf(ang);
    float partner = __shfl_xor(n0, 32);
    float out0 = (d < 32) ? (n0 * cs - partner * sn) : (n0 * cs + partner * sn);
    row[d]      = (unsigned short)f2b(out0);
    row[d + 64] = (unsigned short)f2b(n1);
}

// ============ pass 1: per-chunk KV outer product  Wt[e][d] = sum_j kdec_j V[j][e] K[j][d]
// grid = B*NH*NC = 1024 blocks, 256 threads.
__global__ __launch_bounds__(256) void chunk_kv(const unsigned short* __restrict__ qkv,
                                                unsigned short* __restrict__ wbuf)
{
    __shared__ unsigned short kt[128 * 72];   // kt[d][j]
    __shared__ unsigned short vt[128 * 72];   // vt[e][j] * kdec[j]
    int bi = blockIdx.x;
    int c = bi & 31, bh = bi >> 5, h = bh & 15, b = bh >> 4;
    int tid = threadIdx.x;
    float slope = -exp2f(-0.5f * (float)(h + 1)) * (1.0f + 1e-5f);

    const unsigned short* kbase = qkv + ((size_t)(b * S_ + c * CHUNK_)) * NKV + HID + h * HD;
    const unsigned short* vbase = kbase + HID;

    for (int idx = tid; idx < 4096; idx += 256) {
        int j = idx >> 6, p = idx & 63;
        unsigned int ku = *(const unsigned int*)(kbase + (size_t)j * NKV + p * 2);
        kt[(2 * p) * 72 + j]     = (unsigned short)(ku & 0xffffu);
        kt[(2 * p + 1) * 72 + j] = (unsigned short)(ku >> 16);
        float kd = expf(slope * (float)(63 - j));
        unsigned int vu = *(const unsigned int*)(vbase + (size_t)j * NKV + p * 2);
        vt[(2 * p) * 72 + j]     = (unsigned short)f2b(b2f(vu) * kd);
        vt[(2 * p + 1) * 72 + j] = (unsigned short)f2b(b2f(vu >> 16) * kd);
    }
    __syncthreads();

    int lane = tid & 63, wave = tid >> 6;
    int wm = (wave >> 1) * 64;     // e
    int wn = (wave & 1) * 64;      // d
    int l16 = lane & 15, quad = lane >> 4;

    f32x4 acc[4][4];
    #pragma unroll
    for (int i = 0; i < 4; ++i)
        #pragma unroll
        for (int j = 0; j < 4; ++j) { f32x4 z = {0.f,0.f,0.f,0.f}; acc[i][j] = z; }

    #pragma unroll
    for (int ks = 0; ks < 64; ks += 32) {
        bf16x8 af[4], bf[4];
        #pragma unroll
        for (int t = 0; t < 4; ++t) {
            af[t] = *(const bf16x8*)((const bf16_t*)vt + (wm + t * 16 + l16) * 72 + ks + quad * 8);
            bf[t] = *(const bf16x8*)((const bf16_t*)kt + (wn + t * 16 + l16) * 72 + ks + quad * 8);
        }
        #pragma unroll
        for (int mt = 0; mt < 4; ++mt)
            #pragma unroll
            for (int nt = 0; nt < 4; ++nt)
                acc[mt][nt] = __builtin_amdgcn_mfma_f32_16x16x32_bf16(af[mt], bf[nt], acc[mt][nt], 0, 0, 0);
    }

    unsigned short* wp = wbuf + ((size_t)bi << 14);  // [e][d] 128x128
    #pragma unroll
    for (int mt = 0; mt < 4; ++mt)
        #pragma unroll
        for (int nt = 0; nt < 4; ++nt) {
            int dcol = wn + nt * 16 + l16;
            #pragma unroll
            for (int r = 0; r < 4; ++r) {
                int erow = wm + mt * 16 + quad * 4 + r;
                wp[(size_t)erow * 128 + dcol] = (unsigned short)f2b(acc[mt][nt][r]);
            }
        }
}

// ============ pass 2: sequential state scan over chunks (linear recurrence)
// grid = B*NH*4 = 128 blocks: each handles (b,h, 32-row e-slice). State in regs.
// Emits St_prev (state BEFORE chunk c) as bf16 [e][d] per chunk.
__global__ __launch_bounds__(256) void state_scan(const unsigned short* __restrict__ wbuf,
                                                  const float* __restrict__ rs0,
                                                  unsigned short* __restrict__ stbuf)
{
    int bi = blockIdx.x;
    int es = bi & 3, bh = bi >> 2, h = bh & 15, b = bh >> 4;
    int tid = threadIdx.x;
    float slope = -exp2f(-0.5f * (float)(h + 1)) * (1.0f + 1e-5f);
    float lam = expf(slope * 64.0f);

    int e  = es * 32 + (tid >> 3);
    int d0 = (tid & 7) * 16;

    float S[16];
    const float* rp = rs0 + ((size_t)(b * NH + h)) * HD * HD + e;   // rstate[b][h][d][e]
    #pragma unroll
    for (int t = 0; t < 16; ++t) S[t] = rp[(size_t)(d0 + t) * HD];

    size_t off = (size_t)e * 128 + d0;
    for (int c = 0; c < NC; ++c) {
        size_t base = (((size_t)bh * NC + c) << 14) + off;
        uint4 o0, o1;
        o0.x = f2b(S[0])  | (f2b(S[1])  << 16);
        o0.y = f2b(S[2])  | (f2b(S[3])  << 16);
        o0.z = f2b(S[4])  | (f2b(S[5])  << 16);
        o0.w = f2b(S[6])  | (f2b(S[7])  << 16);
        o1.x = f2b(S[8])  | (f2b(S[9])  << 16);
        o1.y = f2b(S[10]) | (f2b(S[11]) << 16);
        o1.z = f2b(S[12]) | (f2b(S[13]) << 16);
        o1.w = f2b(S[14]) | (f2b(S[15]) << 16);
        *(uint4*)(stbuf + base)     = o0;
        *(uint4*)(stbuf + base + 8) = o1;
        uint4 w0 = *(const uint4*)(wbuf + base);
        uint4 w1 = *(const uint4*)(wbuf + base + 8);
        const unsigned int wu[8] = {w0.x, w0.y, w0.z, w0.w, w1.x, w1.y, w1.z, w1.w};
        #pragma unroll
        for (int t = 0; t < 8; ++t) {
            S[2 * t]     = S[2 * t]     * lam + b2f(wu[t]);
            S[2 * t + 1] = S[2 * t + 1] * lam + b2f(wu[t] >> 16);
        }
    }
}

// ============ pass 3: per-chunk output  O = (mask.QK^T)@V + qdec*(Q@S_prev)
// grid = B*NH*NC = 1024 blocks, 256 threads (4 waves, each a 32-col e-slice).
__global__ __launch_bounds__(256) void chunk_out(const unsigned short* __restrict__ qkv,
                                                 const unsigned short* __restrict__ stbuf,
                                                 unsigned short* __restrict__ obuf)
{
    __shared__ unsigned short qs[64 * 136];   // q[i][d]
    __shared__ unsigned short ks[64 * 136];   // k[j][d]
    __shared__ unsigned short vt[128 * 72];   // v^T[e][j]
    __shared__ unsigned short sc[64 * 72];    // masked scores [i][j]

    int bi = blockIdx.x;
    int c = bi & 31, bh = bi >> 5, h = bh & 15, b = bh >> 4;
    int tid = threadIdx.x;
    float slope = -exp2f(-0.5f * (float)(h + 1)) * (1.0f + 1e-5f);

    const unsigned short* qrow = qkv + ((size_t)(b * S_ + c * CHUNK_)) * NKV + h * HD;
    // stage q,k (rows of 128, padded stride 136)
    for (int idx = tid; idx < 1024; idx += 256) {
        int row = idx >> 4, c8 = (idx & 15) * 8;
        *(uint4*)(qs + row * 136 + c8) = *(const uint4*)(qrow + (size_t)row * NKV + c8);
        *(uint4*)(ks + row * 136 + c8) = *(const uint4*)(qrow + (size_t)row * NKV + HID + c8);
    }
    // stage v transposed
    const unsigned short* vbase = qrow + 2 * HID;
    for (int idx = tid; idx < 4096; idx += 256) {
        int j = idx >> 6, p = idx & 63;
        unsigned int vu = *(const unsigned int*)(vbase + (size_t)j * NKV + p * 2);
        vt[(2 * p) * 72 + j]     = (unsigned short)(vu & 0xffffu);
        vt[(2 * p + 1) * 72 + j] = (unsigned short)(vu >> 16);
    }
    __syncthreads();

    int lane = tid & 63, wave = tid >> 6;
    int l16 = lane & 15, quad = lane >> 4;

    // ---- scores: each wave computes rows [wave*16, +16) x all 64 j ----
    {
        f32x4 accS[4];
        #pragma unroll
        for (int t = 0; t < 4; ++t) { f32x4 z = {0.f,0.f,0.f,0.f}; accS[t] = z; }
        #pragma unroll
        for (int ksp = 0; ksp < 128; ksp += 32) {
            bf16x8 aq = *(const bf16x8*)((const bf16_t*)qs + (wave * 16 + l16) * 136 + ksp + quad * 8);
            #pragma unroll
            for (int nt = 0; nt < 4; ++nt) {
                bf16x8 bk = *(const bf16x8*)((const bf16_t*)ks + (nt * 16 + l16) * 136 + ksp + quad * 8);
                accS[nt] = __builtin_amdgcn_mfma_f32_16x16x32_bf16(aq, bk, accS[nt], 0, 0, 0);
            }
        }
        float ad[4];
        #pragma unroll
        for (int r = 0; r < 4; ++r) ad[r] = expf(slope * (float)(wave * 16 + quad * 4 + r));
        #pragma unroll
        for (int nt = 0; nt < 4; ++nt) {
            int j = nt * 16 + l16;
            float bd = expf(-slope * (float)j);
            #pragma unroll
            for (int r = 0; r < 4; ++r) {
                int i = wave * 16 + quad * 4 + r;
                float v = (i >= j) ? accS[nt][r] * ad[r] * bd : 0.0f;
                sc[i * 72 + j] = (unsigned short)f2b(v);
            }
        }
    }
    __syncthreads();

    // ---- intra + inter: wave handles e-slice [wave*32, +32), all 64 i rows ----
    int wn3 = wave * 32;
    const unsigned short* stp = stbuf + (((size_t)bh * NC + c) << 14);

    f32x4 accI[4][2], accE[4][2];
    #pragma unroll
    for (int i = 0; i < 4; ++i)
        #pragma unroll
        for (int j = 0; j < 2; ++j) { f32x4 z = {0.f,0.f,0.f,0.f}; accI[i][j] = z; accE[i][j] = z; }

    // intra: K = 64 (j)
    #pragma unroll
    for (int ksp = 0; ksp < 64; ksp += 32) {
        bf16x8 as[4], bv[2];
        #pragma unroll
        for (int mt = 0; mt < 4; ++mt)
            as[mt] = *(const bf16x8*)((const bf16_t*)sc + (mt * 16 + l16) * 72 + ksp + quad * 8);
        #pragma unroll
        for (int nt = 0; nt < 2; ++nt)
            bv[nt] = *(const bf16x8*)((const bf16_t*)vt + (wn3 + nt * 16 + l16) * 72 + ksp + quad * 8);
        #pragma unroll
        for (int mt = 0; mt < 4; ++mt)
            #pragma unroll
            for (int nt = 0; nt < 2; ++nt)
                accI[mt][nt] = __builtin_amdgcn_mfma_f32_16x16x32_bf16(as[mt], bv[nt], accI[mt][nt], 0, 0, 0);
    }
    // inter: K = 128 (d), B-frags direct from global stbuf [e][d]
    #pragma unroll
    for (int ksp = 0; ksp < 128; ksp += 32) {
        bf16x8 aq[4], bs[2];
        #pragma unroll
        for (int mt = 0; mt < 4; ++mt)
            aq[mt] = *(const bf16x8*)((const bf16_t*)qs + (mt * 16 + l16) * 136 + ksp + quad * 8);
        #pragma unroll
        for (int nt = 0; nt < 2; ++nt)
            bs[nt] = *(const bf16x8*)((const bf16_t*)stp + (size_t)(wn3 + nt * 16 + l16) * 128 + ksp + quad * 8);
        #pragma unroll
        for (int mt = 0; mt < 4; ++mt)
            #pragma unroll
            for (int nt = 0; nt < 2; ++nt)
                accE[mt][nt] = __builtin_amdgcn_mfma_f32_16x16x32_bf16(aq[mt], bs[nt], accE[mt][nt], 0, 0, 0);
    }

    // epilogue: O = accI + qdec[i]*accE, bf16 store
    #pragma unroll
    for (int mt = 0; mt < 4; ++mt) {
        #pragma unroll
        for (int r = 0; r < 4; ++r) {
            int i = mt * 16 + quad * 4 + r;
            float qd = expf(slope * (float)(i + 1));
            int orow = b * S_ + c * CHUNK_ + i;
            #pragma unroll
            for (int nt = 0; nt < 2; ++nt) {
                int col = h * HD + wn3 + nt * 16 + l16;
                float o = accI[mt][nt][r] + qd * accE[mt][nt][r];
                obuf[(size_t)orow * 2048 + col] = (unsigned short)f2b(o);
            }
        }
    }
}

// ------- group RMSNorm + sigmoid gate: read o bf16 + gate bf16, write bf16 -------
__global__ __launch_bounds__(256) void gnorm_gate(const unsigned short* __restrict__ o,
                                                  unsigned short* __restrict__ gate,
                                                  const float* __restrict__ gw)
{
    int row = blockIdx.x >> 3;
    int g   = blockIdx.x & 7;
    int col = g * 256 + threadIdx.x;
    size_t idx = (size_t)row * 2048 + col;
    float ov = b2f(o[idx]);
    float ss = ov * ov;
    #pragma unroll
    for (int off = 32; off > 0; off >>= 1) ss += __shfl_xor(ss, off);
    __shared__ float part[4];
    if ((threadIdx.x & 63) == 0) part[threadIdx.x >> 6] = ss;
    __syncthreads();
    float tot = part[0] + part[1] + part[2] + part[3];
    float inv = rsqrtf(tot * (1.0f / 256.0f) + 1e-6f);
    float gv = b2f(gate[idx]);
    float sig = 1.0f / (1.0f + expf(-gv));
    gate[idx] = (unsigned short)f2b(ov * inv * gw[col] * sig);
}

// ---------------- launch ----------------
extern "C" void kernel_launch(void* const* d_in, const int* in_sizes, int n_in,
                              void* d_out, int out_size, void* d_ws, size_t ws_size,
                              hipStream_t stream) {
    const int*   positions = (const int*)d_in[0];
    const float* hidden    = (const float*)d_in[1];
    const float* rstate    = (const float*)d_in[2];
    const float* w_qkv     = (const float*)d_in[3];
    const float* w_g       = (const float*)d_in[4];
    const float* w_dense   = (const float*)d_in[5];
    const float* q_norm_w  = (const float*)d_in[6];
    const float* k_norm_w  = (const float*)d_in[7];
    const float* g_norm_w  = (const float*)d_in[8];
    float* out = (float*)d_out;

    const int MR = B_ * S_;  // 4096

    // ---- ws layout (total 159,383,552 B — same as round 3) ----
    char* w = (char*)d_ws;
    unsigned short* qkv  = (unsigned short*)w;            w += (size_t)MR * NKV * 2;     // 50.3 MB
    unsigned short* gbuf = (unsigned short*)w;            w += (size_t)MR * 2048 * 2;    // 16.8 MB
    unsigned short* wdT  = (unsigned short*)w;            w += (size_t)HID * HID * 2;    // 8.4 MB
    unsigned short* wgT  = (unsigned short*)w;            w += (size_t)HID * HID * 2;    // 8.4 MB
    char* regionA = w;                                    w += (size_t)MR * HID * 2 + (size_t)NKV * HID * 2; // 41.9 MB
    char* regionB = w;                                    // 33.6 MB (wbuf)
    unsigned short* hbf   = (unsigned short*)regionA;                       // consumed by GEMMs
    unsigned short* wqT   = (unsigned short*)(regionA + (size_t)MR * HID * 2);
    unsigned short* stbuf = (unsigned short*)regionA;                       // 32 MB, after GEMMs
    unsigned short* wbuf  = (unsigned short*)regionB;                       // 32 MB
    unsigned short* obuf  = (unsigned short*)regionB;                       // 16.8 MB, after pass2

    // ---- conversions ----
    cvt_bf16<<<dim3((MR * HID / 8 + 255) / 256), dim3(256), 0, stream>>>(hidden, hbf, MR * HID / 8);
    transpose_cvt<<<dim3((HID / 32) * (NKV / 32)), dim3(256), 0, stream>>>(w_qkv, wqT, HID, NKV);
    transpose_cvt<<<dim3((HID / 32) * (HID / 32)), dim3(256), 0, stream>>>(w_g, wgT, HID, HID);
    transpose_cvt<<<dim3((HID / 32) * (HID / 32)), dim3(256), 0, stream>>>(w_dense, wdT, HID, HID);

    // ---- projections ----
    gemm_mfma<unsigned short><<<dim3((MR / 128) * (NKV / 128)), dim3(256), 0, stream>>>(
        (const bf16_t*)hbf, (const bf16_t*)wqT, qkv, MR, NKV, HID);
    gemm_mfma<unsigned short><<<dim3((MR / 128) * (HID / 128)), dim3(256), 0, stream>>>(
        (const bf16_t*)hbf, (const bf16_t*)wgT, gbuf, MR, HID, HID);
    // ---- q/k norm + rope (in place) ----
    norm_rope<<<dim3(B_ * S_ * NH * 2), dim3(64), 0, stream>>>(qkv, positions, q_norm_w, k_norm_w);

    // ---- attention: 3-pass chunked scan ----
    chunk_kv<<<dim3(B_ * NH * NC), dim3(256), 0, stream>>>(qkv, wbuf);
    state_scan<<<dim3(B_ * NH * 4), dim3(256), 0, stream>>>(wbuf, rstate, stbuf);
    chunk_out<<<dim3(B_ * NH * NC), dim3(256), 0, stream>>>(qkv, stbuf, obuf);

    // ---- group norm + gate ----
    gnorm_gate<<<dim3(MR * GROUPS_), dim3(256), 0, stream>>>(obuf, gbuf, g_norm_w);
    // ---- output projection (fp32 out) ----
    gemm_mfma<float><<<dim3((MR / 128) * (HID / 128)), dim3(256), 0, stream>>>(
        (const bf16_t*)gbuf, (const bf16_t*)wdT, out, MR, HID, HID);
}

// Round 5
// 509.541 us; speedup vs baseline: 6.1290x; 1.0200x over previous
//
#include <hip/hip_runtime.h>
#include <hip/hip_bf16.h>
#include <math.h>

// ---- problem constants ----
#define NH   16
#define HD   128
#define HID  2048
#define NKV  6144      // 3*NH*HD
#define B_   2
#define S_   2048
#define NC   32        // S/CHUNK
#define CHUNK_ 64
#define GROUPS_ 8

typedef __bf16 bf16_t;
typedef bf16_t bf16x8 __attribute__((ext_vector_type(8)));
typedef float  f32x4  __attribute__((ext_vector_type(4)));

__device__ __forceinline__ float b2f(unsigned int u) {
    union { unsigned int u; float f; } c; c.u = (u & 0xffffu) << 16; return c.f;
}
__device__ __forceinline__ unsigned int f2b(float f) {
    union { float f; unsigned int u; } c; c.f = f;
    unsigned int u = c.u;
    return (u + 0x7fffu + ((u >> 16) & 1u)) >> 16;
}

#define GLOAD_LDS16(gp, lp) __builtin_amdgcn_global_load_lds(                     \
    (const __attribute__((address_space(1))) void*)(gp),                          \
    (__attribute__((address_space(3))) void*)(lp), 16, 0, 0)

// ---------------- fp32 -> bf16 elementwise (8 elems/thread) ----------------
__global__ __launch_bounds__(256) void cvt_bf16(const float* __restrict__ in,
                                                unsigned short* __restrict__ out, int n8)
{
    int i = blockIdx.x * 256 + threadIdx.x;
    if (i >= n8) return;
    const float4* p = (const float4*)in + (size_t)i * 2;
    float4 a = p[0], b = p[1];
    uint4 o;
    o.x = f2b(a.x) | (f2b(a.y) << 16);
    o.y = f2b(a.z) | (f2b(a.w) << 16);
    o.z = f2b(b.x) | (f2b(b.y) << 16);
    o.w = f2b(b.z) | (f2b(b.w) << 16);
    ((uint4*)out)[i] = o;
}

// ------------- fp32 [K][N] -> bf16 [N][K] transpose (32x32 tiles) ---------------
__global__ __launch_bounds__(256) void transpose_cvt(const float* __restrict__ in,
                                                     unsigned short* __restrict__ out,
                                                     int Kdim, int Ndim)
{
    __shared__ float tile[32][33];
    int ntx = Ndim >> 5;
    int bx = blockIdx.x % ntx;
    int by = blockIdx.x / ntx;
    int lx = threadIdx.x & 31, ly = threadIdx.x >> 5;
    int r0 = by * 32, c0 = bx * 32;
    #pragma unroll
    for (int r = 0; r < 4; ++r)
        tile[ly + r * 8][lx] = in[(size_t)(r0 + ly + r * 8) * Ndim + c0 + lx];
    __syncthreads();
    #pragma unroll
    for (int r = 0; r < 4; ++r)
        out[(size_t)(c0 + ly + r * 8) * Kdim + r0 + lx] = (unsigned short)f2b(tile[lx][ly + r * 8]);
}

// ---------------- MFMA GEMM: C[M,N] = A[M,K] @ Bt[N,K]^T ----------------
__device__ __forceinline__ void storeOne(float* p, float v) { *p = v; }
__device__ __forceinline__ void storeOne(unsigned short* p, float v) { *p = (unsigned short)f2b(v); }

template <typename OutT>
__global__ __launch_bounds__(256) void gemm_mfma(const bf16_t* __restrict__ A,   // [M][K]
                                                 const bf16_t* __restrict__ Bt,  // [N][K]
                                                 OutT* __restrict__ C,           // [M][N]
                                                 int M, int N, int K)
{
    __shared__ bf16_t As[128 * 32];
    __shared__ bf16_t Bs[128 * 32];
    int tid  = threadIdx.x;
    int ntiles = N >> 7;
    int bx = blockIdx.x % ntiles;
    int by = blockIdx.x / ntiles;
    int lane = tid & 63;
    int wave = tid >> 6;
    int wm = (wave >> 1) * 64;
    int wn = (wave & 1) * 64;
    int l16  = lane & 15;
    int quad = lane >> 4;

    f32x4 acc[4][4];
    #pragma unroll
    for (int i = 0; i < 4; ++i)
        #pragma unroll
        for (int j = 0; j < 4; ++j) { f32x4 z = {0.f, 0.f, 0.f, 0.f}; acc[i][j] = z; }

    const bf16_t* aG = A  + (size_t)(by * 128 + (tid >> 2)) * K + (tid & 3) * 8;
    const bf16_t* bG = Bt + (size_t)(bx * 128 + (tid >> 2)) * K + (tid & 3) * 8;
    bf16_t* aL0 = As + tid * 8;
    bf16_t* aL1 = As + 2048 + tid * 8;
    bf16_t* bL0 = Bs + tid * 8;
    bf16_t* bL1 = Bs + 2048 + tid * 8;
    const size_t half = (size_t)64 * K;

    for (int kt = 0; kt < K; kt += 32) {
        GLOAD_LDS16(aG + kt,        aL0);
        GLOAD_LDS16(aG + half + kt, aL1);
        GLOAD_LDS16(bG + kt,        bL0);
        GLOAD_LDS16(bG + half + kt, bL1);
        __syncthreads();
        bf16x8 af[4], bf[4];
        #pragma unroll
        for (int t = 0; t < 4; ++t) {
            af[t] = *(const bf16x8*)(As + (wm + t * 16 + l16) * 32 + quad * 8);
            bf[t] = *(const bf16x8*)(Bs + (wn + t * 16 + l16) * 32 + quad * 8);
        }
        #pragma unroll
        for (int mt = 0; mt < 4; ++mt)
            #pragma unroll
            for (int nt = 0; nt < 4; ++nt)
                acc[mt][nt] = __builtin_amdgcn_mfma_f32_16x16x32_bf16(af[mt], bf[nt], acc[mt][nt], 0, 0, 0);
        __syncthreads();
    }

    #pragma unroll
    for (int mt = 0; mt < 4; ++mt)
        #pragma unroll
        for (int nt = 0; nt < 4; ++nt) {
            int col = bx * 128 + wn + nt * 16 + l16;
            #pragma unroll
            for (int r = 0; r < 4; ++r) {
                int row = by * 128 + wm + mt * 16 + quad * 4 + r;
                storeOne(C + (size_t)row * N + col, acc[mt][nt][r]);
            }
        }
}

// ------- q/k RMSNorm + partial RoPE, in place. grid = B*S blocks of 256. -------
// Pass 0: all 16 q heads; pass 1: all 16 k heads. 16 lanes per head-row.
__global__ __launch_bounds__(256) void norm_rope(unsigned short* __restrict__ qkv,
                                                 const int* __restrict__ positions,
                                                 const float* __restrict__ qw,
                                                 const float* __restrict__ kw)
{
    int bs = blockIdx.x;
    int s  = bs & (S_ - 1);
    int tid = threadIdx.x;
    int l16 = tid & 15;
    unsigned short* base = qkv + (size_t)bs * NKV;
    float pos = (float)positions[s];

    #pragma unroll
    for (int p = 0; p < 2; ++p) {
        int rr = p * 16 + (tid >> 4);   // 0..31
        int qk = rr >> 4;
        int h  = rr & 15;
        unsigned short* row = base + qk * HID + h * HD;
        const float* w = qk ? kw : qw;
        uint4 v = *(const uint4*)(row + l16 * 8);
        float x[8];
        x[0] = b2f(v.x); x[1] = b2f(v.x >> 16);
        x[2] = b2f(v.y); x[3] = b2f(v.y >> 16);
        x[4] = b2f(v.z); x[5] = b2f(v.z >> 16);
        x[6] = b2f(v.w); x[7] = b2f(v.w >> 16);
        float ss = 0.f;
        #pragma unroll
        for (int t = 0; t < 8; ++t) ss += x[t] * x[t];
        ss += __shfl_xor(ss, 1); ss += __shfl_xor(ss, 2);
        ss += __shfl_xor(ss, 4); ss += __shfl_xor(ss, 8);
        float inv = rsqrtf(ss * (1.0f / 128.0f) + 1e-6f);
        float n[8];
        #pragma unroll
        for (int t = 0; t < 8; ++t) n[t] = x[t] * inv * w[l16 * 8 + t];
        float pr[8];
        #pragma unroll
        for (int t = 0; t < 8; ++t) pr[t] = __shfl_xor(n[t], 4);   // dims +-32
        if (l16 < 8) {
            #pragma unroll
            for (int t = 0; t < 8; ++t) {
                int dim = l16 * 8 + t;
                int i = dim & 31;
                float ang = pos * exp2f(-(float)i * 0.4152410118609203f);
                float cs = cosf(ang), sn = sinf(ang);
                n[t] = (dim < 32) ? (n[t] * cs - pr[t] * sn) : (n[t] * cs + pr[t] * sn);
            }
        }
        uint4 o;
        o.x = f2b(n[0]) | (f2b(n[1]) << 16);
        o.y = f2b(n[2]) | (f2b(n[3]) << 16);
        o.z = f2b(n[4]) | (f2b(n[5]) << 16);
        o.w = f2b(n[6]) | (f2b(n[7]) << 16);
        *(uint4*)(row + l16 * 8) = o;
    }
}

// ============ pass 1: per-chunk KV outer product  Wt[e][d] = sum_j kdec_j V[j][e] K[j][d]
// grid = B*NH*NC = 1024 blocks, 256 threads.
__global__ __launch_bounds__(256) void chunk_kv(const unsigned short* __restrict__ qkv,
                                                unsigned short* __restrict__ wbuf)
{
    __shared__ unsigned short kt[128 * 72];   // kt[d][j]
    __shared__ unsigned short vt[128 * 72];   // vt[e][j] * kdec[j]
    int bi = blockIdx.x;
    int c = bi & 31, bh = bi >> 5, h = bh & 15, b = bh >> 4;
    int tid = threadIdx.x;
    float slope = -exp2f(-0.5f * (float)(h + 1)) * (1.0f + 1e-5f);

    const unsigned short* kbase = qkv + ((size_t)(b * S_ + c * CHUNK_)) * NKV + HID + h * HD;
    const unsigned short* vbase = kbase + HID;

    for (int idx = tid; idx < 4096; idx += 256) {
        int j = idx >> 6, p = idx & 63;
        unsigned int ku = *(const unsigned int*)(kbase + (size_t)j * NKV + p * 2);
        kt[(2 * p) * 72 + j]     = (unsigned short)(ku & 0xffffu);
        kt[(2 * p + 1) * 72 + j] = (unsigned short)(ku >> 16);
        float kd = expf(slope * (float)(63 - j));
        unsigned int vu = *(const unsigned int*)(vbase + (size_t)j * NKV + p * 2);
        vt[(2 * p) * 72 + j]     = (unsigned short)f2b(b2f(vu) * kd);
        vt[(2 * p + 1) * 72 + j] = (unsigned short)f2b(b2f(vu >> 16) * kd);
    }
    __syncthreads();

    int lane = tid & 63, wave = tid >> 6;
    int wm = (wave >> 1) * 64;     // e
    int wn = (wave & 1) * 64;      // d
    int l16 = lane & 15, quad = lane >> 4;

    f32x4 acc[4][4];
    #pragma unroll
    for (int i = 0; i < 4; ++i)
        #pragma unroll
        for (int j = 0; j < 4; ++j) { f32x4 z = {0.f,0.f,0.f,0.f}; acc[i][j] = z; }

    #pragma unroll
    for (int ks = 0; ks < 64; ks += 32) {
        bf16x8 af[4], bf[4];
        #pragma unroll
        for (int t = 0; t < 4; ++t) {
            af[t] = *(const bf16x8*)((const bf16_t*)vt + (wm + t * 16 + l16) * 72 + ks + quad * 8);
            bf[t] = *(const bf16x8*)((const bf16_t*)kt + (wn + t * 16 + l16) * 72 + ks + quad * 8);
        }
        #pragma unroll
        for (int mt = 0; mt < 4; ++mt)
            #pragma unroll
            for (int nt = 0; nt < 4; ++nt)
                acc[mt][nt] = __builtin_amdgcn_mfma_f32_16x16x32_bf16(af[mt], bf[nt], acc[mt][nt], 0, 0, 0);
    }

    unsigned short* wp = wbuf + ((size_t)bi << 14);  // [e][d] 128x128
    #pragma unroll
    for (int mt = 0; mt < 4; ++mt)
        #pragma unroll
        for (int nt = 0; nt < 4; ++nt) {
            int dcol = wn + nt * 16 + l16;
            #pragma unroll
            for (int r = 0; r < 4; ++r) {
                int erow = wm + mt * 16 + quad * 4 + r;
                wp[(size_t)erow * 128 + dcol] = (unsigned short)f2b(acc[mt][nt][r]);
            }
        }
}

// ============ pass 2: sequential state scan (linear recurrence), 512 blocks
// Each block: (b,h, 8-row e-slice). 4 fp32 state/thread. Emits pre-state bf16 [e][d].
__global__ __launch_bounds__(256) void state_scan(const unsigned short* __restrict__ wbuf,
                                                  const float* __restrict__ rs0,
                                                  unsigned short* __restrict__ stbuf)
{
    int bi = blockIdx.x;
    int es = bi & 15, bh = bi >> 4, h = bh & 15, b = bh >> 4;
    int tid = threadIdx.x;
    float slope = -exp2f(-0.5f * (float)(h + 1)) * (1.0f + 1e-5f);
    float lam = expf(slope * 64.0f);

    int e  = es * 8 + (tid >> 5);
    int d0 = (tid & 31) * 4;

    float S[4];
    const float* rp = rs0 + ((size_t)(b * NH + h)) * HD * HD + e;   // rstate[b][h][d][e]
    #pragma unroll
    for (int t = 0; t < 4; ++t) S[t] = rp[(size_t)(d0 + t) * HD];

    size_t off = (size_t)e * 128 + d0;
    for (int c = 0; c < NC; ++c) {
        size_t base = (((size_t)bh * NC + c) << 14) + off;
        uint2 o;
        o.x = f2b(S[0]) | (f2b(S[1]) << 16);
        o.y = f2b(S[2]) | (f2b(S[3]) << 16);
        *(uint2*)(stbuf + base) = o;
        uint2 w = *(const uint2*)(wbuf + base);
        S[0] = S[0] * lam + b2f(w.x);
        S[1] = S[1] * lam + b2f(w.x >> 16);
        S[2] = S[2] * lam + b2f(w.y);
        S[3] = S[3] * lam + b2f(w.y >> 16);
    }
}

// ============ pass 3: per-chunk output  O = (mask.QK^T)@V + qdec*(Q@S_prev)
// grid = B*NH*NC = 1024 blocks, 256 threads. k/state B-frags read from global.
__global__ __launch_bounds__(256) void chunk_out(const unsigned short* __restrict__ qkv,
                                                 const unsigned short* __restrict__ stbuf,
                                                 unsigned short* __restrict__ obuf)
{
    __shared__ unsigned short qs[64 * 136];   // q[i][d]
    __shared__ unsigned short vt[128 * 72];   // v^T[e][j]
    __shared__ unsigned short sc[64 * 72];    // masked scores [i][j]

    int bi = blockIdx.x;
    int c = bi & 31, bh = bi >> 5, h = bh & 15, b = bh >> 4;
    int tid = threadIdx.x;
    float slope = -exp2f(-0.5f * (float)(h + 1)) * (1.0f + 1e-5f);

    const unsigned short* qrow = qkv + ((size_t)(b * S_ + c * CHUNK_)) * NKV + h * HD;
    const unsigned short* krow = qrow + HID;
    // stage q (rows of 128, padded stride 136)
    for (int idx = tid; idx < 1024; idx += 256) {
        int row = idx >> 4, c8 = (idx & 15) * 8;
        *(uint4*)(qs + row * 136 + c8) = *(const uint4*)(qrow + (size_t)row * NKV + c8);
    }
    // stage v transposed
    const unsigned short* vbase = qrow + 2 * HID;
    for (int idx = tid; idx < 4096; idx += 256) {
        int j = idx >> 6, p = idx & 63;
        unsigned int vu = *(const unsigned int*)(vbase + (size_t)j * NKV + p * 2);
        vt[(2 * p) * 72 + j]     = (unsigned short)(vu & 0xffffu);
        vt[(2 * p + 1) * 72 + j] = (unsigned short)(vu >> 16);
    }
    __syncthreads();

    int lane = tid & 63, wave = tid >> 6;
    int l16 = lane & 15, quad = lane >> 4;

    // ---- scores: each wave computes rows [wave*16, +16) x all 64 j; k-frags global ----
    {
        f32x4 accS[4];
        #pragma unroll
        for (int t = 0; t < 4; ++t) { f32x4 z = {0.f,0.f,0.f,0.f}; accS[t] = z; }
        #pragma unroll
        for (int ksp = 0; ksp < 128; ksp += 32) {
            bf16x8 aq = *(const bf16x8*)((const bf16_t*)qs + (wave * 16 + l16) * 136 + ksp + quad * 8);
            #pragma unroll
            for (int nt = 0; nt < 4; ++nt) {
                bf16x8 bk = *(const bf16x8*)((const bf16_t*)krow + (size_t)(nt * 16 + l16) * NKV + ksp + quad * 8);
                accS[nt] = __builtin_amdgcn_mfma_f32_16x16x32_bf16(aq, bk, accS[nt], 0, 0, 0);
            }
        }
        float ad[4];
        #pragma unroll
        for (int r = 0; r < 4; ++r) ad[r] = expf(slope * (float)(wave * 16 + quad * 4 + r));
        #pragma unroll
        for (int nt = 0; nt < 4; ++nt) {
            int j = nt * 16 + l16;
            float bd = expf(-slope * (float)j);
            #pragma unroll
            for (int r = 0; r < 4; ++r) {
                int i = wave * 16 + quad * 4 + r;
                float v = (i >= j) ? accS[nt][r] * ad[r] * bd : 0.0f;
                sc[i * 72 + j] = (unsigned short)f2b(v);
            }
        }
    }
    __syncthreads();

    // ---- intra + inter: wave handles e-slice [wave*32, +32), all 64 i rows ----
    int wn3 = wave * 32;
    const unsigned short* stp = stbuf + (((size_t)bh * NC + c) << 14);

    f32x4 accI[4][2], accE[4][2];
    #pragma unroll
    for (int i = 0; i < 4; ++i)
        #pragma unroll
        for (int j = 0; j < 2; ++j) { f32x4 z = {0.f,0.f,0.f,0.f}; accI[i][j] = z; accE[i][j] = z; }

    // intra: K = 64 (j)
    #pragma unroll
    for (int ksp = 0; ksp < 64; ksp += 32) {
        bf16x8 as[4], bv[2];
        #pragma unroll
        for (int mt = 0; mt < 4; ++mt)
            as[mt] = *(const bf16x8*)((const bf16_t*)sc + (mt * 16 + l16) * 72 + ksp + quad * 8);
        #pragma unroll
        for (int nt = 0; nt < 2; ++nt)
            bv[nt] = *(const bf16x8*)((const bf16_t*)vt + (wn3 + nt * 16 + l16) * 72 + ksp + quad * 8);
        #pragma unroll
        for (int mt = 0; mt < 4; ++mt)
            #pragma unroll
            for (int nt = 0; nt < 2; ++nt)
                accI[mt][nt] = __builtin_amdgcn_mfma_f32_16x16x32_bf16(as[mt], bv[nt], accI[mt][nt], 0, 0, 0);
    }
    // inter: K = 128 (d), B-frags direct from global stbuf [e][d]
    #pragma unroll
    for (int ksp = 0; ksp < 128; ksp += 32) {
        bf16x8 aq[4], bs[2];
        #pragma unroll
        for (int mt = 0; mt < 4; ++mt)
            aq[mt] = *(const bf16x8*)((const bf16_t*)qs + (mt * 16 + l16) * 136 + ksp + quad * 8);
        #pragma unroll
        for (int nt = 0; nt < 2; ++nt)
            bs[nt] = *(const bf16x8*)((const bf16_t*)stp + (size_t)(wn3 + nt * 16 + l16) * 128 + ksp + quad * 8);
        #pragma unroll
        for (int mt = 0; mt < 4; ++mt)
            #pragma unroll
            for (int nt = 0; nt < 2; ++nt)
                accE[mt][nt] = __builtin_amdgcn_mfma_f32_16x16x32_bf16(aq[mt], bs[nt], accE[mt][nt], 0, 0, 0);
    }

    // epilogue: O = accI + qdec[i]*accE, bf16 store
    #pragma unroll
    for (int mt = 0; mt < 4; ++mt) {
        #pragma unroll
        for (int r = 0; r < 4; ++r) {
            int i = mt * 16 + quad * 4 + r;
            float qd = expf(slope * (float)(i + 1));
            int orow = b * S_ + c * CHUNK_ + i;
            #pragma unroll
            for (int nt = 0; nt < 2; ++nt) {
                int col = h * HD + wn3 + nt * 16 + l16;
                float o = accI[mt][nt][r] + qd * accE[mt][nt][r];
                obuf[(size_t)orow * 2048 + col] = (unsigned short)f2b(o);
            }
        }
    }
}

// ------- group RMSNorm + sigmoid gate: read o bf16 + gate bf16, write bf16 -------
__global__ __launch_bounds__(256) void gnorm_gate(const unsigned short* __restrict__ o,
                                                  unsigned short* __restrict__ gate,
                                                  const float* __restrict__ gw)
{
    int row = blockIdx.x >> 3;
    int g   = blockIdx.x & 7;
    int col = g * 256 + threadIdx.x;
    size_t idx = (size_t)row * 2048 + col;
    float ov = b2f(o[idx]);
    float ss = ov * ov;
    #pragma unroll
    for (int off = 32; off > 0; off >>= 1) ss += __shfl_xor(ss, off);
    __shared__ float part[4];
    if ((threadIdx.x & 63) == 0) part[threadIdx.x >> 6] = ss;
    __syncthreads();
    float tot = part[0] + part[1] + part[2] + part[3];
    float inv = rsqrtf(tot * (1.0f / 256.0f) + 1e-6f);
    float gv = b2f(gate[idx]);
    float sig = 1.0f / (1.0f + expf(-gv));
    gate[idx] = (unsigned short)f2b(ov * inv * gw[col] * sig);
}

// ---------------- launch ----------------
extern "C" void kernel_launch(void* const* d_in, const int* in_sizes, int n_in,
                              void* d_out, int out_size, void* d_ws, size_t ws_size,
                              hipStream_t stream) {
    const int*   positions = (const int*)d_in[0];
    const float* hidden    = (const float*)d_in[1];
    const float* rstate    = (const float*)d_in[2];
    const float* w_qkv     = (const float*)d_in[3];
    const float* w_g       = (const float*)d_in[4];
    const float* w_dense   = (const float*)d_in[5];
    const float* q_norm_w  = (const float*)d_in[6];
    const float* k_norm_w  = (const float*)d_in[7];
    const float* g_norm_w  = (const float*)d_in[8];
    float* out = (float*)d_out;

    const int MR = B_ * S_;  // 4096

    // ---- ws layout (total 159,383,552 B — unchanged) ----
    char* w = (char*)d_ws;
    unsigned short* qkv  = (unsigned short*)w;            w += (size_t)MR * NKV * 2;     // 50.3 MB
    unsigned short* gbuf = (unsigned short*)w;            w += (size_t)MR * 2048 * 2;    // 16.8 MB
    unsigned short* wdT  = (unsigned short*)w;            w += (size_t)HID * HID * 2;    // 8.4 MB
    unsigned short* wgT  = (unsigned short*)w;            w += (size_t)HID * HID * 2;    // 8.4 MB
    char* regionA = w;                                    w += (size_t)MR * HID * 2 + (size_t)NKV * HID * 2; // 41.9 MB
    char* regionB = w;                                    // 33.6 MB (wbuf)
    unsigned short* hbf   = (unsigned short*)regionA;
    unsigned short* wqT   = (unsigned short*)(regionA + (size_t)MR * HID * 2);
    unsigned short* stbuf = (unsigned short*)regionA;     // 32 MB, after GEMMs
    unsigned short* wbuf  = (unsigned short*)regionB;     // 32 MB
    unsigned short* obuf  = (unsigned short*)regionB;     // 16.8 MB, after pass2

    // ---- conversions ----
    cvt_bf16<<<dim3((MR * HID / 8 + 255) / 256), dim3(256), 0, stream>>>(hidden, hbf, MR * HID / 8);
    transpose_cvt<<<dim3((HID / 32) * (NKV / 32)), dim3(256), 0, stream>>>(w_qkv, wqT, HID, NKV);
    transpose_cvt<<<dim3((HID / 32) * (HID / 32)), dim3(256), 0, stream>>>(w_g, wgT, HID, HID);
    transpose_cvt<<<dim3((HID / 32) * (HID / 32)), dim3(256), 0, stream>>>(w_dense, wdT, HID, HID);

    // ---- projections ----
    gemm_mfma<unsigned short><<<dim3((MR / 128) * (NKV / 128)), dim3(256), 0, stream>>>(
        (const bf16_t*)hbf, (const bf16_t*)wqT, qkv, MR, NKV, HID);
    gemm_mfma<unsigned short><<<dim3((MR / 128) * (HID / 128)), dim3(256), 0, stream>>>(
        (const bf16_t*)hbf, (const bf16_t*)wgT, gbuf, MR, HID, HID);
    // ---- q/k norm + rope (in place) ----
    norm_rope<<<dim3(B_ * S_), dim3(256), 0, stream>>>(qkv, positions, q_norm_w, k_norm_w);

    // ---- attention: 3-pass chunked scan ----
    chunk_kv<<<dim3(B_ * NH * NC), dim3(256), 0, stream>>>(qkv, wbuf);
    state_scan<<<dim3(B_ * NH * 16), dim3(256), 0, stream>>>(wbuf, rstate, stbuf);
    chunk_out<<<dim3(B_ * NH * NC), dim3(256), 0, stream>>>(qkv, stbuf, obuf);

    // ---- group norm + gate ----
    gnorm_gate<<<dim3(MR * GROUPS_), dim3(256), 0, stream>>>(obuf, gbuf, g_norm_w);
    // ---- output projection (fp32 out) ----
    gemm_mfma<float><<<dim3((MR / 128) * (HID / 128)), dim3(256), 0, stream>>>(
        (const bf16_t*)gbuf, (const bf16_t*)wdT, out, MR, HID, HID);
}

// Round 6
// 482.631 us; speedup vs baseline: 6.4707x; 1.0558x over previous
//
#include <hip/hip_runtime.h>
#include <hip/hip_bf16.h>
#include <math.h>

// ---- problem constants ----
#define NH   16
#define HD   128
#define HID  2048
#define NKV  6144      // 3*NH*HD
#define B_   2
#define S_   2048
#define NC   32        // S/CHUNK
#define CHUNK_ 64
#define GROUPS_ 8

typedef __bf16 bf16_t;
typedef bf16_t bf16x8 __attribute__((ext_vector_type(8)));
typedef float  f32x4  __attribute__((ext_vector_type(4)));

__device__ __forceinline__ float b2f(unsigned int u) {
    union { unsigned int u; float f; } c; c.u = (u & 0xffffu) << 16; return c.f;
}
__device__ __forceinline__ unsigned int f2b(float f) {
    union { float f; unsigned int u; } c; c.f = f;
    unsigned int u = c.u;
    return (u + 0x7fffu + ((u >> 16) & 1u)) >> 16;
}

#define GLOAD_LDS16(gp, lp) __builtin_amdgcn_global_load_lds(                     \
    (const __attribute__((address_space(1))) void*)(gp),                          \
    (__attribute__((address_space(3))) void*)(lp), 16, 0, 0)

// ---------------- fp32 -> bf16 elementwise (8 elems/thread) ----------------
__global__ __launch_bounds__(256) void cvt_bf16(const float* __restrict__ in,
                                                unsigned short* __restrict__ out, int n8)
{
    int i = blockIdx.x * 256 + threadIdx.x;
    if (i >= n8) return;
    const float4* p = (const float4*)in + (size_t)i * 2;
    float4 a = p[0], b = p[1];
    uint4 o;
    o.x = f2b(a.x) | (f2b(a.y) << 16);
    o.y = f2b(a.z) | (f2b(a.w) << 16);
    o.z = f2b(b.x) | (f2b(b.y) << 16);
    o.w = f2b(b.z) | (f2b(b.w) << 16);
    ((uint4*)out)[i] = o;
}

// ------------- fp32 [K][N] -> bf16 [N][K] transpose (32x32 tiles) ---------------
__global__ __launch_bounds__(256) void transpose_cvt(const float* __restrict__ in,
                                                     unsigned short* __restrict__ out,
                                                     int Kdim, int Ndim)
{
    __shared__ float tile[32][33];
    int ntx = Ndim >> 5;
    int bx = blockIdx.x % ntx;
    int by = blockIdx.x / ntx;
    int lx = threadIdx.x & 31, ly = threadIdx.x >> 5;
    int r0 = by * 32, c0 = bx * 32;
    #pragma unroll
    for (int r = 0; r < 4; ++r)
        tile[ly + r * 8][lx] = in[(size_t)(r0 + ly + r * 8) * Ndim + c0 + lx];
    __syncthreads();
    #pragma unroll
    for (int r = 0; r < 4; ++r)
        out[(size_t)(c0 + ly + r * 8) * Kdim + r0 + lx] = (unsigned short)f2b(tile[lx][ly + r * 8]);
}

// ---------------- MFMA GEMM (plain): C[M,N] = A[M,K] @ Bt[N,K]^T ----------------
__device__ __forceinline__ void storeOne(float* p, float v) { *p = v; }
__device__ __forceinline__ void storeOne(unsigned short* p, float v) { *p = (unsigned short)f2b(v); }

template <typename OutT>
__global__ __launch_bounds__(256) void gemm_mfma(const bf16_t* __restrict__ A,   // [M][K]
                                                 const bf16_t* __restrict__ Bt,  // [N][K]
                                                 OutT* __restrict__ C,           // [M][N]
                                                 int M, int N, int K)
{
    __shared__ bf16_t As[128 * 32];
    __shared__ bf16_t Bs[128 * 32];
    int tid  = threadIdx.x;
    int ntiles = N >> 7;
    int bx = blockIdx.x % ntiles;
    int by = blockIdx.x / ntiles;
    int lane = tid & 63;
    int wave = tid >> 6;
    int wm = (wave >> 1) * 64;
    int wn = (wave & 1) * 64;
    int l16  = lane & 15;
    int quad = lane >> 4;

    f32x4 acc[4][4];
    #pragma unroll
    for (int i = 0; i < 4; ++i)
        #pragma unroll
        for (int j = 0; j < 4; ++j) { f32x4 z = {0.f, 0.f, 0.f, 0.f}; acc[i][j] = z; }

    const bf16_t* aG = A  + (size_t)(by * 128 + (tid >> 2)) * K + (tid & 3) * 8;
    const bf16_t* bG = Bt + (size_t)(bx * 128 + (tid >> 2)) * K + (tid & 3) * 8;
    bf16_t* aL0 = As + tid * 8;
    bf16_t* aL1 = As + 2048 + tid * 8;
    bf16_t* bL0 = Bs + tid * 8;
    bf16_t* bL1 = Bs + 2048 + tid * 8;
    const size_t half = (size_t)64 * K;

    for (int kt = 0; kt < K; kt += 32) {
        GLOAD_LDS16(aG + kt,        aL0);
        GLOAD_LDS16(aG + half + kt, aL1);
        GLOAD_LDS16(bG + kt,        bL0);
        GLOAD_LDS16(bG + half + kt, bL1);
        __syncthreads();
        bf16x8 af[4], bf[4];
        #pragma unroll
        for (int t = 0; t < 4; ++t) {
            af[t] = *(const bf16x8*)(As + (wm + t * 16 + l16) * 32 + quad * 8);
            bf[t] = *(const bf16x8*)(Bs + (wn + t * 16 + l16) * 32 + quad * 8);
        }
        #pragma unroll
        for (int mt = 0; mt < 4; ++mt)
            #pragma unroll
            for (int nt = 0; nt < 4; ++nt)
                acc[mt][nt] = __builtin_amdgcn_mfma_f32_16x16x32_bf16(af[mt], bf[nt], acc[mt][nt], 0, 0, 0);
        __syncthreads();
    }

    #pragma unroll
    for (int mt = 0; mt < 4; ++mt)
        #pragma unroll
        for (int nt = 0; nt < 4; ++nt) {
            int col = bx * 128 + wn + nt * 16 + l16;
            #pragma unroll
            for (int r = 0; r < 4; ++r) {
                int row = by * 128 + wm + mt * 16 + quad * 4 + r;
                storeOne(C + (size_t)row * N + col, acc[mt][nt][r]);
            }
        }
}

// -------- fused QKV+gate GEMM: A[4096][2048] @ Bt[8192][2048]^T, routed output ---
// cols [0,6144) -> Cq (stride 6144), cols [6144,8192) -> Cg (stride 2048). bf16 out.
__global__ __launch_bounds__(256) void gemm_mfma_qg(const bf16_t* __restrict__ A,
                                                    const bf16_t* __restrict__ Bt,
                                                    unsigned short* __restrict__ Cq,
                                                    unsigned short* __restrict__ Cg)
{
    __shared__ bf16_t As[128 * 32];
    __shared__ bf16_t Bs[128 * 32];
    const int K = HID;
    int tid  = threadIdx.x;
    int bx = blockIdx.x & 63;          // 64 col tiles (8192/128)
    int by = blockIdx.x >> 6;          // 32 row tiles
    int lane = tid & 63;
    int wave = tid >> 6;
    int wm = (wave >> 1) * 64;
    int wn = (wave & 1) * 64;
    int l16  = lane & 15;
    int quad = lane >> 4;

    f32x4 acc[4][4];
    #pragma unroll
    for (int i = 0; i < 4; ++i)
        #pragma unroll
        for (int j = 0; j < 4; ++j) { f32x4 z = {0.f, 0.f, 0.f, 0.f}; acc[i][j] = z; }

    const bf16_t* aG = A  + (size_t)(by * 128 + (tid >> 2)) * K + (tid & 3) * 8;
    const bf16_t* bG = Bt + (size_t)(bx * 128 + (tid >> 2)) * K + (tid & 3) * 8;
    bf16_t* aL0 = As + tid * 8;
    bf16_t* aL1 = As + 2048 + tid * 8;
    bf16_t* bL0 = Bs + tid * 8;
    bf16_t* bL1 = Bs + 2048 + tid * 8;
    const size_t half = (size_t)64 * K;

    for (int kt = 0; kt < K; kt += 32) {
        GLOAD_LDS16(aG + kt,        aL0);
        GLOAD_LDS16(aG + half + kt, aL1);
        GLOAD_LDS16(bG + kt,        bL0);
        GLOAD_LDS16(bG + half + kt, bL1);
        __syncthreads();
        bf16x8 af[4], bf[4];
        #pragma unroll
        for (int t = 0; t < 4; ++t) {
            af[t] = *(const bf16x8*)(As + (wm + t * 16 + l16) * 32 + quad * 8);
            bf[t] = *(const bf16x8*)(Bs + (wn + t * 16 + l16) * 32 + quad * 8);
        }
        #pragma unroll
        for (int mt = 0; mt < 4; ++mt)
            #pragma unroll
            for (int nt = 0; nt < 4; ++nt)
                acc[mt][nt] = __builtin_amdgcn_mfma_f32_16x16x32_bf16(af[mt], bf[nt], acc[mt][nt], 0, 0, 0);
        __syncthreads();
    }

    int col0 = bx * 128;
    unsigned short* C;
    int N, colbase;
    if (col0 < NKV) { C = Cq; N = NKV; colbase = col0; }
    else            { C = Cg; N = HID; colbase = col0 - NKV; }

    #pragma unroll
    for (int mt = 0; mt < 4; ++mt)
        #pragma unroll
        for (int nt = 0; nt < 4; ++nt) {
            int col = colbase + wn + nt * 16 + l16;
            #pragma unroll
            for (int r = 0; r < 4; ++r) {
                int row = by * 128 + wm + mt * 16 + quad * 4 + r;
                C[(size_t)row * N + col] = (unsigned short)f2b(acc[mt][nt][r]);
            }
        }
}

// ------- q/k RMSNorm + partial RoPE, in place. grid = B*S blocks of 256. -------
__global__ __launch_bounds__(256) void norm_rope(unsigned short* __restrict__ qkv,
                                                 const int* __restrict__ positions,
                                                 const float* __restrict__ qw,
                                                 const float* __restrict__ kw)
{
    int bs = blockIdx.x;
    int s  = bs & (S_ - 1);
    int tid = threadIdx.x;
    int l16 = tid & 15;
    unsigned short* base = qkv + (size_t)bs * NKV;
    float pos = (float)positions[s];

    #pragma unroll
    for (int p = 0; p < 2; ++p) {
        int rr = p * 16 + (tid >> 4);   // 0..31
        int qk = rr >> 4;
        int h  = rr & 15;
        unsigned short* row = base + qk * HID + h * HD;
        const float* w = qk ? kw : qw;
        uint4 v = *(const uint4*)(row + l16 * 8);
        float x[8];
        x[0] = b2f(v.x); x[1] = b2f(v.x >> 16);
        x[2] = b2f(v.y); x[3] = b2f(v.y >> 16);
        x[4] = b2f(v.z); x[5] = b2f(v.z >> 16);
        x[6] = b2f(v.w); x[7] = b2f(v.w >> 16);
        float ss = 0.f;
        #pragma unroll
        for (int t = 0; t < 8; ++t) ss += x[t] * x[t];
        ss += __shfl_xor(ss, 1); ss += __shfl_xor(ss, 2);
        ss += __shfl_xor(ss, 4); ss += __shfl_xor(ss, 8);
        float inv = rsqrtf(ss * (1.0f / 128.0f) + 1e-6f);
        float n[8];
        #pragma unroll
        for (int t = 0; t < 8; ++t) n[t] = x[t] * inv * w[l16 * 8 + t];
        float pr[8];
        #pragma unroll
        for (int t = 0; t < 8; ++t) pr[t] = __shfl_xor(n[t], 4);   // dims +-32
        if (l16 < 8) {
            #pragma unroll
            for (int t = 0; t < 8; ++t) {
                int dim = l16 * 8 + t;
                int i = dim & 31;
                float ang = pos * exp2f(-(float)i * 0.4152410118609203f);
                float cs = cosf(ang), sn = sinf(ang);
                n[t] = (dim < 32) ? (n[t] * cs - pr[t] * sn) : (n[t] * cs + pr[t] * sn);
            }
        }
        uint4 o;
        o.x = f2b(n[0]) | (f2b(n[1]) << 16);
        o.y = f2b(n[2]) | (f2b(n[3]) << 16);
        o.z = f2b(n[4]) | (f2b(n[5]) << 16);
        o.w = f2b(n[6]) | (f2b(n[7]) << 16);
        *(uint4*)(row + l16 * 8) = o;
    }
}

// ============ pass 1: per-chunk KV outer product  Wt[e][d] = sum_j kdec_j V[j][e] K[j][d]
__global__ __launch_bounds__(256) void chunk_kv(const unsigned short* __restrict__ qkv,
                                                unsigned short* __restrict__ wbuf)
{
    __shared__ unsigned short kt[128 * 72];   // kt[d][j]
    __shared__ unsigned short vt[128 * 72];   // vt[e][j] * kdec[j]
    int bi = blockIdx.x;
    int c = bi & 31, bh = bi >> 5, h = bh & 15, b = bh >> 4;
    int tid = threadIdx.x;
    float slope = -exp2f(-0.5f * (float)(h + 1)) * (1.0f + 1e-5f);

    const unsigned short* kbase = qkv + ((size_t)(b * S_ + c * CHUNK_)) * NKV + HID + h * HD;
    const unsigned short* vbase = kbase + HID;

    for (int idx = tid; idx < 4096; idx += 256) {
        int j = idx >> 6, p = idx & 63;
        unsigned int ku = *(const unsigned int*)(kbase + (size_t)j * NKV + p * 2);
        kt[(2 * p) * 72 + j]     = (unsigned short)(ku & 0xffffu);
        kt[(2 * p + 1) * 72 + j] = (unsigned short)(ku >> 16);
        float kd = expf(slope * (float)(63 - j));
        unsigned int vu = *(const unsigned int*)(vbase + (size_t)j * NKV + p * 2);
        vt[(2 * p) * 72 + j]     = (unsigned short)f2b(b2f(vu) * kd);
        vt[(2 * p + 1) * 72 + j] = (unsigned short)f2b(b2f(vu >> 16) * kd);
    }
    __syncthreads();

    int lane = tid & 63, wave = tid >> 6;
    int wm = (wave >> 1) * 64;     // e
    int wn = (wave & 1) * 64;      // d
    int l16 = lane & 15, quad = lane >> 4;

    f32x4 acc[4][4];
    #pragma unroll
    for (int i = 0; i < 4; ++i)
        #pragma unroll
        for (int j = 0; j < 4; ++j) { f32x4 z = {0.f,0.f,0.f,0.f}; acc[i][j] = z; }

    #pragma unroll
    for (int ks = 0; ks < 64; ks += 32) {
        bf16x8 af[4], bf[4];
        #pragma unroll
        for (int t = 0; t < 4; ++t) {
            af[t] = *(const bf16x8*)((const bf16_t*)vt + (wm + t * 16 + l16) * 72 + ks + quad * 8);
            bf[t] = *(const bf16x8*)((const bf16_t*)kt + (wn + t * 16 + l16) * 72 + ks + quad * 8);
        }
        #pragma unroll
        for (int mt = 0; mt < 4; ++mt)
            #pragma unroll
            for (int nt = 0; nt < 4; ++nt)
                acc[mt][nt] = __builtin_amdgcn_mfma_f32_16x16x32_bf16(af[mt], bf[nt], acc[mt][nt], 0, 0, 0);
    }

    unsigned short* wp = wbuf + ((size_t)bi << 14);  // [e][d] 128x128
    #pragma unroll
    for (int mt = 0; mt < 4; ++mt)
        #pragma unroll
        for (int nt = 0; nt < 4; ++nt) {
            int dcol = wn + nt * 16 + l16;
            #pragma unroll
            for (int r = 0; r < 4; ++r) {
                int erow = wm + mt * 16 + quad * 4 + r;
                wp[(size_t)erow * 128 + dcol] = (unsigned short)f2b(acc[mt][nt][r]);
            }
        }
}

// ============ pass 2: sequential state scan (linear recurrence), 512 blocks
__global__ __launch_bounds__(256) void state_scan(const unsigned short* __restrict__ wbuf,
                                                  const float* __restrict__ rs0,
                                                  unsigned short* __restrict__ stbuf)
{
    int bi = blockIdx.x;
    int es = bi & 15, bh = bi >> 4, h = bh & 15, b = bh >> 4;
    int tid = threadIdx.x;
    float slope = -exp2f(-0.5f * (float)(h + 1)) * (1.0f + 1e-5f);
    float lam = expf(slope * 64.0f);

    int e  = es * 8 + (tid >> 5);
    int d0 = (tid & 31) * 4;

    float S[4];
    const float* rp = rs0 + ((size_t)(b * NH + h)) * HD * HD + e;   // rstate[b][h][d][e]
    #pragma unroll
    for (int t = 0; t < 4; ++t) S[t] = rp[(size_t)(d0 + t) * HD];

    size_t off = (size_t)e * 128 + d0;
    for (int c = 0; c < NC; ++c) {
        size_t base = (((size_t)bh * NC + c) << 14) + off;
        uint2 o;
        o.x = f2b(S[0]) | (f2b(S[1]) << 16);
        o.y = f2b(S[2]) | (f2b(S[3]) << 16);
        *(uint2*)(stbuf + base) = o;
        uint2 w = *(const uint2*)(wbuf + base);
        S[0] = S[0] * lam + b2f(w.x);
        S[1] = S[1] * lam + b2f(w.x >> 16);
        S[2] = S[2] * lam + b2f(w.y);
        S[3] = S[3] * lam + b2f(w.y >> 16);
    }
}

// ============ pass 3: per-chunk output  O = (mask.QK^T)@V + qdec*(Q@S_prev)
__global__ __launch_bounds__(256) void chunk_out(const unsigned short* __restrict__ qkv,
                                                 const unsigned short* __restrict__ stbuf,
                                                 unsigned short* __restrict__ obuf)
{
    __shared__ unsigned short qs[64 * 136];   // q[i][d]
    __shared__ unsigned short vt[128 * 72];   // v^T[e][j]
    __shared__ unsigned short sc[64 * 72];    // masked scores [i][j]

    int bi = blockIdx.x;
    int c = bi & 31, bh = bi >> 5, h = bh & 15, b = bh >> 4;
    int tid = threadIdx.x;
    float slope = -exp2f(-0.5f * (float)(h + 1)) * (1.0f + 1e-5f);

    int lane = tid & 63, wave = tid >> 6;
    int l16 = lane & 15, quad = lane >> 4;
    int wn3 = wave * 32;

    // ---- prefetch st B-frags into registers FIRST: HBM latency (~900cyc) hides
    //      behind staging + scores + intra phases.
    const unsigned short* stp = stbuf + (((size_t)bh * NC + c) << 14);
    bf16x8 bsf[4][2];
    #pragma unroll
    for (int ksp4 = 0; ksp4 < 4; ++ksp4)
        #pragma unroll
        for (int nt = 0; nt < 2; ++nt)
            bsf[ksp4][nt] = *(const bf16x8*)((const bf16_t*)stp +
                (size_t)(wn3 + nt * 16 + l16) * 128 + ksp4 * 32 + quad * 8);

    const unsigned short* qrow = qkv + ((size_t)(b * S_ + c * CHUNK_)) * NKV + h * HD;
    const unsigned short* krow = qrow + HID;
    // stage q (rows of 128, padded stride 136)
    for (int idx = tid; idx < 1024; idx += 256) {
        int row = idx >> 4, c8 = (idx & 15) * 8;
        *(uint4*)(qs + row * 136 + c8) = *(const uint4*)(qrow + (size_t)row * NKV + c8);
    }
    // stage v transposed
    const unsigned short* vbase = qrow + 2 * HID;
    for (int idx = tid; idx < 4096; idx += 256) {
        int j = idx >> 6, p = idx & 63;
        unsigned int vu = *(const unsigned int*)(vbase + (size_t)j * NKV + p * 2);
        vt[(2 * p) * 72 + j]     = (unsigned short)(vu & 0xffffu);
        vt[(2 * p + 1) * 72 + j] = (unsigned short)(vu >> 16);
    }
    __syncthreads();

    // ---- scores: each wave computes rows [wave*16, +16) x all 64 j; k-frags global ----
    {
        f32x4 accS[4];
        #pragma unroll
        for (int t = 0; t < 4; ++t) { f32x4 z = {0.f,0.f,0.f,0.f}; accS[t] = z; }
        #pragma unroll
        for (int ksp = 0; ksp < 128; ksp += 32) {
            bf16x8 aq = *(const bf16x8*)((const bf16_t*)qs + (wave * 16 + l16) * 136 + ksp + quad * 8);
            #pragma unroll
            for (int nt = 0; nt < 4; ++nt) {
                bf16x8 bk = *(const bf16x8*)((const bf16_t*)krow + (size_t)(nt * 16 + l16) * NKV + ksp + quad * 8);
                accS[nt] = __builtin_amdgcn_mfma_f32_16x16x32_bf16(aq, bk, accS[nt], 0, 0, 0);
            }
        }
        float ad[4];
        #pragma unroll
        for (int r = 0; r < 4; ++r) ad[r] = expf(slope * (float)(wave * 16 + quad * 4 + r));
        #pragma unroll
        for (int nt = 0; nt < 4; ++nt) {
            int j = nt * 16 + l16;
            float bd = expf(-slope * (float)j);
            #pragma unroll
            for (int r = 0; r < 4; ++r) {
                int i = wave * 16 + quad * 4 + r;
                float v = (i >= j) ? accS[nt][r] * ad[r] * bd : 0.0f;
                sc[i * 72 + j] = (unsigned short)f2b(v);
            }
        }
    }
    __syncthreads();

    f32x4 accI[4][2], accE[4][2];
    #pragma unroll
    for (int i = 0; i < 4; ++i)
        #pragma unroll
        for (int j = 0; j < 2; ++j) { f32x4 z = {0.f,0.f,0.f,0.f}; accI[i][j] = z; accE[i][j] = z; }

    // intra: K = 64 (j)
    #pragma unroll
    for (int ksp = 0; ksp < 64; ksp += 32) {
        bf16x8 as[4], bv[2];
        #pragma unroll
        for (int mt = 0; mt < 4; ++mt)
            as[mt] = *(const bf16x8*)((const bf16_t*)sc + (mt * 16 + l16) * 72 + ksp + quad * 8);
        #pragma unroll
        for (int nt = 0; nt < 2; ++nt)
            bv[nt] = *(const bf16x8*)((const bf16_t*)vt + (wn3 + nt * 16 + l16) * 72 + ksp + quad * 8);
        #pragma unroll
        for (int mt = 0; mt < 4; ++mt)
            #pragma unroll
            for (int nt = 0; nt < 2; ++nt)
                accI[mt][nt] = __builtin_amdgcn_mfma_f32_16x16x32_bf16(as[mt], bv[nt], accI[mt][nt], 0, 0, 0);
    }
    // inter: K = 128 (d), B-frags already in registers (bsf)
    #pragma unroll
    for (int ksp4 = 0; ksp4 < 4; ++ksp4) {
        bf16x8 aq[4];
        #pragma unroll
        for (int mt = 0; mt < 4; ++mt)
            aq[mt] = *(const bf16x8*)((const bf16_t*)qs + (mt * 16 + l16) * 136 + ksp4 * 32 + quad * 8);
        #pragma unroll
        for (int mt = 0; mt < 4; ++mt)
            #pragma unroll
            for (int nt = 0; nt < 2; ++nt)
                accE[mt][nt] = __builtin_amdgcn_mfma_f32_16x16x32_bf16(aq[mt], bsf[ksp4][nt], accE[mt][nt], 0, 0, 0);
    }

    // epilogue: O = accI + qdec[i]*accE, bf16 store
    #pragma unroll
    for (int mt = 0; mt < 4; ++mt) {
        #pragma unroll
        for (int r = 0; r < 4; ++r) {
            int i = mt * 16 + quad * 4 + r;
            float qd = expf(slope * (float)(i + 1));
            int orow = b * S_ + c * CHUNK_ + i;
            #pragma unroll
            for (int nt = 0; nt < 2; ++nt) {
                int col = h * HD + wn3 + nt * 16 + l16;
                float o = accI[mt][nt][r] + qd * accE[mt][nt][r];
                obuf[(size_t)orow * 2048 + col] = (unsigned short)f2b(o);
            }
        }
    }
}

// ------- group RMSNorm + sigmoid gate: read o bf16 + gate bf16, write bf16 -------
__global__ __launch_bounds__(256) void gnorm_gate(const unsigned short* __restrict__ o,
                                                  unsigned short* __restrict__ gate,
                                                  const float* __restrict__ gw)
{
    int row = blockIdx.x >> 3;
    int g   = blockIdx.x & 7;
    int col = g * 256 + threadIdx.x;
    size_t idx = (size_t)row * 2048 + col;
    float ov = b2f(o[idx]);
    float ss = ov * ov;
    #pragma unroll
    for (int off = 32; off > 0; off >>= 1) ss += __shfl_xor(ss, off);
    __shared__ float part[4];
    if ((threadIdx.x & 63) == 0) part[threadIdx.x >> 6] = ss;
    __syncthreads();
    float tot = part[0] + part[1] + part[2] + part[3];
    float inv = rsqrtf(tot * (1.0f / 256.0f) + 1e-6f);
    float gv = b2f(gate[idx]);
    float sig = 1.0f / (1.0f + expf(-gv));
    gate[idx] = (unsigned short)f2b(ov * inv * gw[col] * sig);
}

// ---------------- launch ----------------
extern "C" void kernel_launch(void* const* d_in, const int* in_sizes, int n_in,
                              void* d_out, int out_size, void* d_ws, size_t ws_size,
                              hipStream_t stream) {
    const int*   positions = (const int*)d_in[0];
    const float* hidden    = (const float*)d_in[1];
    const float* rstate    = (const float*)d_in[2];
    const float* w_qkv     = (const float*)d_in[3];
    const float* w_g       = (const float*)d_in[4];
    const float* w_dense   = (const float*)d_in[5];
    const float* q_norm_w  = (const float*)d_in[6];
    const float* k_norm_w  = (const float*)d_in[7];
    const float* g_norm_w  = (const float*)d_in[8];
    float* out = (float*)d_out;

    const int MR = B_ * S_;  // 4096

    // ---- ws layout (total 159,383,552 B — unchanged) ----
    char* w = (char*)d_ws;
    unsigned short* qkv  = (unsigned short*)w;            w += (size_t)MR * NKV * 2;     // 50.3 MB
    unsigned short* gbuf = (unsigned short*)w;            w += (size_t)MR * 2048 * 2;    // 16.8 MB
    unsigned short* wdT  = (unsigned short*)w;            w += (size_t)HID * HID * 2;    // 8.4 MB
    char* regionA = w;                                    w += (size_t)MR * HID * 2 + (size_t)8192 * HID * 2; // 50.3 MB
    char* regionB = w;                                    // 33.6 MB
    unsigned short* hbf   = (unsigned short*)regionA;                                 // 16.8 MB
    unsigned short* btQG  = (unsigned short*)(regionA + (size_t)MR * HID * 2);        // [8192][2048] 33.5 MB
    unsigned short* wqT   = btQG;                                                     // rows 0..6143
    unsigned short* wgT   = btQG + (size_t)NKV * HID;                                 // rows 6144..8191
    unsigned short* stbuf = (unsigned short*)regionA;     // 32 MB, after GEMMs
    unsigned short* wbuf  = (unsigned short*)regionB;     // 32 MB
    unsigned short* obuf  = (unsigned short*)regionB;     // 16.8 MB, after pass2

    // ---- conversions ----
    cvt_bf16<<<dim3((MR * HID / 8 + 255) / 256), dim3(256), 0, stream>>>(hidden, hbf, MR * HID / 8);
    transpose_cvt<<<dim3((HID / 32) * (NKV / 32)), dim3(256), 0, stream>>>(w_qkv, wqT, HID, NKV);
    transpose_cvt<<<dim3((HID / 32) * (HID / 32)), dim3(256), 0, stream>>>(w_g, wgT, HID, HID);
    transpose_cvt<<<dim3((HID / 32) * (HID / 32)), dim3(256), 0, stream>>>(w_dense, wdT, HID, HID);

    // ---- fused qkv+gate projection (2048 blocks) ----
    gemm_mfma_qg<<<dim3(32 * 64), dim3(256), 0, stream>>>(
        (const bf16_t*)hbf, (const bf16_t*)btQG, qkv, gbuf);
    // ---- q/k norm + rope (in place) ----
    norm_rope<<<dim3(B_ * S_), dim3(256), 0, stream>>>(qkv, positions, q_norm_w, k_norm_w);

    // ---- attention: 3-pass chunked scan ----
    chunk_kv<<<dim3(B_ * NH * NC), dim3(256), 0, stream>>>(qkv, wbuf);
    state_scan<<<dim3(B_ * NH * 16), dim3(256), 0, stream>>>(wbuf, rstate, stbuf);
    chunk_out<<<dim3(B_ * NH * NC), dim3(256), 0, stream>>>(qkv, stbuf, obuf);

    // ---- group norm + gate ----
    gnorm_gate<<<dim3(MR * GROUPS_), dim3(256), 0, stream>>>(obuf, gbuf, g_norm_w);
    // ---- output projection (fp32 out) ----
    gemm_mfma<float><<<dim3((MR / 128) * (HID / 128)), dim3(256), 0, stream>>>(
        (const bf16_t*)gbuf, (const bf16_t*)wdT, out, MR, HID, HID);
}